// Round 14
// baseline (1796.051 us; speedup 1.0000x reference)
//
#include <hip/hip_runtime.h>

#define BB 32
#define NPTS0 2048
#define KNB 16
#define KC 256   // key-chunk size for two-pass kNN

constexpr int ilog2c(int n){ int l=0; while(n>1){ n>>=1; ++l; } return l; }

static __device__ __forceinline__ float sq3(float a, float b, float c){
  return __fadd_rn(__fadd_rn(__fmul_rn(a,a),__fmul_rn(b,b)),__fmul_rn(c,c));
}

// DPP helpers (templated ctrl/mask; bound_ctrl=false -> masked/invalid lanes keep own
// value, idempotent for max/min).
template<int CTRL, int RM>
static __device__ __forceinline__ float dpp_maxf(float v){
  int s = __builtin_amdgcn_update_dpp(__float_as_int(v), __float_as_int(v), CTRL, RM, 0xF, false);
  return fmaxf(v, __int_as_float(s));
}
template<int CTRL, int RM>
static __device__ __forceinline__ unsigned dpp_minu(unsigned v){
  unsigned s = (unsigned)__builtin_amdgcn_update_dpp((int)v, (int)v, CTRL, RM, 0xF, false);
  return s < v ? s : v;
}

// ---------------- proj body ----------------
static __device__ __forceinline__ void proj_body(const float* __restrict__ x,
    const float* __restrict__ w, const float* __restrict__ bias, float* __restrict__ f0,
    int blk)
{
  int gid = blk*256 + threadIdx.x;
  if (gid >= BB*NPTS0) return;
  float x0 = x[gid*3+0], x1 = x[gid*3+1], x2 = x[gid*3+2];
  #pragma unroll
  for (int o = 0; o < 8; ++o){
    float acc = __fmul_rn(w[o*3+0], x0);
    acc = __fmaf_rn(w[o*3+1], x1, acc);
    acc = __fmaf_rn(w[o*3+2], x2, acc);
    f0[gid*8+o] = __fadd_rn(acc, bias[o]);
  }
}

// ---------------- kNN pass 1 body: NAMED-SCALAR top-16 (registers, no allocas) ------
#define KDECL(I) float th##I = __builtin_inff(); int ti##I = 0;
#define KINS(I,J) if (th##I < th##J){ float tv=th##I; th##I=th##J; th##J=tv; \
                                      int tj=ti##I; ti##I=ti##J; ti##J=tj; }
#define KST(I) pd[base+I] = th##I; pi[base+I] = (unsigned char)ti##I;

static __device__ __forceinline__ void knn_part_body(const float* __restrict__ qpts,
    const float* __restrict__ kpts, int Nq, int Nk, int nkc,
    float* __restrict__ pd, unsigned char* __restrict__ pi,
    int b, int qcb, int kc, float4* kk4)
{
  int tid = threadIdx.x;
  {
    int j = kc*KC + tid;                 // Nk is always a multiple of 256
    float a = kpts[(b*Nk+j)*3+0];
    float c = kpts[(b*Nk+j)*3+1];
    float d = kpts[(b*Nk+j)*3+2];
    kk4[tid] = make_float4(a, c, d, sq3(a,c,d));
  }
  __syncthreads();
  int q = qcb*256 + tid;
  if (q >= Nq) return;
  float qx = qpts[(b*Nq+q)*3+0], qy = qpts[(b*Nq+q)*3+1], qz = qpts[(b*Nq+q)*3+2];
  float qq = sq3(qx,qy,qz);
  KDECL(0) KDECL(1) KDECL(2) KDECL(3) KDECL(4) KDECL(5) KDECL(6) KDECL(7)
  KDECL(8) KDECL(9) KDECL(10) KDECL(11) KDECL(12) KDECL(13) KDECL(14) KDECL(15)
  for (int j=0;j<KC;j++){
    float4 k4 = kk4[j];
    float dot = __fmul_rn(qx,k4.x);
    dot = __fmaf_rn(qy,k4.y,dot);
    dot = __fmaf_rn(qz,k4.z,dot);
    float d = __fadd_rn(__fsub_rn(qq, __fmul_rn(2.0f,dot)), k4.w);
    if (d < th15){                        // strict <: equal dist keeps earlier index
      th15 = d; ti15 = j;
      KINS(15,14) KINS(14,13) KINS(13,12) KINS(12,11) KINS(11,10) KINS(10,9)
      KINS(9,8) KINS(8,7) KINS(7,6) KINS(6,5) KINS(5,4) KINS(4,3) KINS(3,2)
      KINS(2,1) KINS(1,0)
    }
  }
  size_t base = ((size_t)(b*Nq+q)*nkc + kc)*KNB;
  KST(0) KST(1) KST(2) KST(3) KST(4) KST(5) KST(6) KST(7)
  KST(8) KST(9) KST(10) KST(11) KST(12) KST(13) KST(14) KST(15)
}

// ---------------- FPS: STANDALONE SINGLE-WAVE kernels ------------------------------
// One wave (64 lanes) per batch: no barriers, no cross-wave merge, no vmem drains.
// Points in named registers (private kernel => private VGPR budget, no spill);
// coords staged once in LDS, winner fetched via one uniform (broadcast) LDS read —
// same-wave lgkmcnt ordering suffices. Selection = exact jnp.argmax: fmaxf chain
// preserves max bits; descending-T equality match keeps lowest per-lane index;
// u32-min reduce picks the lowest global index on ties.
#define REP8(M)  M(0) M(1) M(2) M(3) M(4) M(5) M(6) M(7)
#define REP8D(M) M(7) M(6) M(5) M(4) M(3) M(2) M(1) M(0)
#define REP32(M) REP8(M) M(8) M(9) M(10) M(11) M(12) M(13) M(14) M(15) \
  M(16) M(17) M(18) M(19) M(20) M(21) M(22) M(23) \
  M(24) M(25) M(26) M(27) M(28) M(29) M(30) M(31)
#define REP32D(M) M(31) M(30) M(29) M(28) M(27) M(26) M(25) M(24) \
  M(23) M(22) M(21) M(20) M(19) M(18) M(17) M(16) \
  M(15) M(14) M(13) M(12) M(11) M(10) M(9) M(8) REP8D(M)

#define SW_LOAD(T) float px##T, py##T, pz##T, d##T; { int i_ = T*64 + lane; \
  px##T = P[i_*3+0]; py##T = P[i_*3+1]; pz##T = P[i_*3+2]; \
  p4[i_] = make_float4(px##T, py##T, pz##T, 0.f); \
  float dx_=__fsub_rn(px##T,c0x), dy_=__fsub_rn(py##T,c0y), dz_=__fsub_rn(pz##T,c0z); \
  d##T = sq3(dx_,dy_,dz_); bm = fmaxf(bm, d##T); }
#define SW_MATCH(T) if (d##T == m_w) ci = (unsigned)(T*64 + lane);
#define SW_UPD(T) { float dx_=__fsub_rn(px##T,sx), dy_=__fsub_rn(py##T,sy), dz_=__fsub_rn(pz##T,sz); \
  float nd_=sq3(dx_,dy_,dz_); d##T=fminf(d##T,nd_); bm=fmaxf(bm,d##T); }

#define SW_MAXCHAIN \
    float v = bm; \
    v = dpp_maxf<0x111,0xF>(v); \
    v = dpp_maxf<0x112,0xF>(v); \
    v = dpp_maxf<0x114,0xF>(v); \
    v = dpp_maxf<0x118,0xF>(v); \
    v = dpp_maxf<0x142,0xA>(v); \
    v = dpp_maxf<0x143,0xC>(v); \
    float m_w = __int_as_float(__builtin_amdgcn_readlane(__float_as_int(v), 63)); \
    unsigned ci = 0xFFFFFFFFu;

#define SW_MINCHAIN \
    ci = dpp_minu<0x111,0xF>(ci); \
    ci = dpp_minu<0x112,0xF>(ci); \
    ci = dpp_minu<0x114,0xF>(ci); \
    ci = dpp_minu<0x118,0xF>(ci); \
    ci = dpp_minu<0x142,0xA>(ci); \
    ci = dpp_minu<0x143,0xC>(ci); \
    unsigned idx_w = (unsigned)__builtin_amdgcn_readlane((int)ci, 63);

__global__ __launch_bounds__(64) void fps_sw32_kernel(const float* __restrict__ pts,
    int S, int* __restrict__ oidx)
{
  __shared__ __align__(16) float4 p4[2048];    // 32 KB
  int b = blockIdx.x, lane = threadIdx.x;
  const float* P = pts + (size_t)b*2048*3;
  float c0x = P[0], c0y = P[1], c0z = P[2];
  float bm = -1.0f;
  REP32(SW_LOAD)
  if (lane == 0) oidx[b*S+0] = 0;
  for (int s=1; s<S; ++s){
    SW_MAXCHAIN
    REP32D(SW_MATCH)
    SW_MINCHAIN
    if (lane == 0) oidx[b*S+s] = (int)idx_w;   // no barrier ever -> no drain
    float4 cs = p4[idx_w];                     // uniform broadcast LDS read
    float sx = cs.x, sy = cs.y, sz = cs.z;
    bm = -1.0f;
    REP32(SW_UPD)
  }
}

__global__ __launch_bounds__(64) void fps_sw8_kernel(const float* __restrict__ pts,
    int S, int* __restrict__ oidx)
{
  __shared__ __align__(16) float4 p4[512];     // 8 KB
  int b = blockIdx.x, lane = threadIdx.x;
  const float* P = pts + (size_t)b*512*3;
  float c0x = P[0], c0y = P[1], c0z = P[2];
  float bm = -1.0f;
  REP8(SW_LOAD)
  if (lane == 0) oidx[b*S+0] = 0;
  for (int s=1; s<S; ++s){
    SW_MAXCHAIN
    REP8D(SW_MATCH)
    SW_MINCHAIN
    if (lane == 0) oidx[b*S+s] = (int)idx_w;
    float4 cs = p4[idx_w];
    float sx = cs.x, sy = cs.y, sz = cs.z;
    bm = -1.0f;
    REP8(SW_UPD)
  }
}

// ---------------- fused launch 1: knn1_part (2048) | proj (256) --------------------
__global__ __launch_bounds__(256) void fused1_kernel(const float* __restrict__ x,
    const float* __restrict__ w_in, const float* __restrict__ b_in,
    float* __restrict__ f0, float* __restrict__ pd1, unsigned char* __restrict__ pi1)
{
  __shared__ __align__(16) float4 sm4[KC];
  int bid = blockIdx.x;
  if (bid < 2048){
    int b = bid & 31; int rest = bid >> 5;
    knn_part_body(x, x, 2048, 2048, 8, pd1, pi1, b, rest & 7, rest >> 3, sm4);
  } else {
    proj_body(x, w_in, b_in, f0, bid - 2048);
  }
}

// ---------------- fused launch 2: knn2_part (512) | knn3_part (128) ----------------
__global__ __launch_bounds__(256) void fused2_kernel(const float* __restrict__ coorq1,
    const float* __restrict__ x,
    float* __restrict__ pd2, unsigned char* __restrict__ pi2,
    float* __restrict__ pd3, unsigned char* __restrict__ pi3)
{
  __shared__ __align__(16) float4 sm4[KC];
  int bid = blockIdx.x;
  if (bid < 512){
    int b = bid & 31; int rest = bid >> 5;
    knn_part_body(coorq1, x, 512, 2048, 8, pd2, pi2, b, rest & 1, rest >> 1, sm4);
  } else {
    int r = bid - 512;
    int b = r & 31; int rest = r >> 5;
    knn_part_body(coorq1, coorq1, 512, 512, 2, pd3, pi3, b, rest & 1, rest >> 1, sm4);
  }
}

// ---------------- standalone knn_part (stage 4) ----------------
__global__ __launch_bounds__(256) void knn_part_kernel(const float* __restrict__ qpts,
    const float* __restrict__ kpts, int Nq, int Nk,
    float* __restrict__ pd, unsigned char* __restrict__ pi)
{
  __shared__ __align__(16) float4 kk4[KC];
  knn_part_body(qpts, kpts, Nq, Nk, gridDim.z, pd, pi,
                blockIdx.x, blockIdx.y, blockIdx.z, kk4);
}

// ---------------- kNN pass 2: merge per-chunk sorted candidate lists ----------------
__global__ __launch_bounds__(256) void knn_merge_kernel(const float* __restrict__ pd,
    const unsigned char* __restrict__ pi, int Nq, int nkc, int* __restrict__ oidx)
{
  int gid = blockIdx.x*256 + threadIdx.x;
  if (gid >= BB*Nq) return;               // gid = b*Nq + q
  float th[KNB]; int ti[KNB];
  #pragma unroll
  for (int i=0;i<KNB;i++){ th[i] = __builtin_inff(); ti[i] = 0; }
  size_t base = (size_t)gid*nkc*KNB;
  for (int kc=0;kc<nkc;kc++){
    size_t cb = base + (size_t)kc*KNB;
    for (int i=0;i<KNB;i++){
      float d = pd[cb+i];
      if (d >= th[KNB-1]) break;           // chunk list sorted ascending
      int j = kc*KC + (int)pi[cb+i];
      th[KNB-1] = d; ti[KNB-1] = j;
      #pragma unroll
      for (int m=KNB-1;m>0;--m){
        if (th[m] < th[m-1]){
          float tv=th[m]; th[m]=th[m-1]; th[m-1]=tv;
          int tj=ti[m]; ti[m]=ti[m-1]; ti[m-1]=tj;
        }
      }
    }
  }
  #pragma unroll
  for (int i=0;i<KNB;i++) oidx[gid*KNB + i] = ti[i];
}

// ---------------- per-point GEMV ----------------
template<int C, int O, bool DIFF>
__global__ __launch_bounds__(256) void gemv_kernel(const float* __restrict__ fin,
    const float* __restrict__ W, float* __restrict__ out, int Npts)
{
  constexpr int NT = O/8;
  constexpr int LNT = ilog2c(NT);
  int gid = blockIdx.x*256 + threadIdx.x;
  if (gid >= BB*Npts*NT) return;
  int tile = gid & (NT-1);
  int pn = gid >> LNT;
  const float* frow = fin + pn*C;
  float f[C];
  #pragma unroll
  for (int c=0;c<C;c++) f[c] = frow[c];
  float acc[8];
  const float* wbase = W + (tile*8)*(2*C);
  #pragma unroll
  for (int oo=0;oo<8;oo++){
    const float* wrow = wbase + oo*(2*C);
    float a = 0.f;
    #pragma unroll
    for (int c=0;c<C;c++){
      float wv = DIFF ? __fsub_rn(wrow[C+c], wrow[c]) : wrow[c];
      a = __fmaf_rn(wv, f[c], a);
    }
    acc[oo] = a;
  }
  float* orow = out + pn*O + tile*8;
  #pragma unroll
  for (int oo=0;oo<8;oo++) orow[oo] = acc[oo];
}

// ---------------- GN stats pass v2: one thread per (q,kk) pair ----------------
template<int O>
__global__ __launch_bounds__(256) void stats2_kernel(const float* __restrict__ A,
    const float* __restrict__ Bq, const int* __restrict__ idx, int Nq, int Nk,
    double* __restrict__ part)
{
  constexpr int O4 = O/4;
  int b = blockIdx.x, split = blockIdx.y, nsplit = gridDim.y;
  int qlen = Nq / nsplit, q0 = split*qlen;
  int tid = threadIdx.x;
  int pairs = qlen * KNB;
  double s1[4] = {0.0,0.0,0.0,0.0};
  double s2[4] = {0.0,0.0,0.0,0.0};
  for (int p = tid; p < pairs; p += 256){
    int q = q0 + (p >> 4);
    int kk = p & 15;
    int j = idx[(b*Nq+q)*KNB + kk];
    const float* arow = A + (size_t)(b*Nk+j)*O;
    const float* brow = Bq + (size_t)(b*Nq+q)*O;
    #pragma unroll
    for (int g=0; g<4; ++g){
      float cs1 = 0.f, cs2 = 0.f;
      #pragma unroll
      for (int c=0; c<O4; c+=4){
        float4 a4 = *(const float4*)(arow + g*O4 + c);
        float4 b4 = *(const float4*)(brow + g*O4 + c);
        float y0 = a4.x+b4.x, y1 = a4.y+b4.y, y2 = a4.z+b4.z, y3 = a4.w+b4.w;
        cs1 += ((y0+y1)+(y2+y3));
        cs2 = fmaf(y0,y0,cs2); cs2 = fmaf(y1,y1,cs2);
        cs2 = fmaf(y2,y2,cs2); cs2 = fmaf(y3,y3,cs2);
      }
      s1[g] += (double)cs1;
      s2[g] += (double)cs2;
    }
  }
  #pragma unroll
  for (int m=32;m>0;m>>=1){
    #pragma unroll
    for (int g=0; g<4; ++g){
      s1[g] += __shfl_down(s1[g], m);
      s2[g] += __shfl_down(s2[g], m);
    }
  }
  __shared__ double sh[4][8];
  int lane = tid & 63, w = tid >> 6;
  if (lane == 0){
    #pragma unroll
    for (int g=0; g<4; ++g){ sh[w][g*2] = s1[g]; sh[w][g*2+1] = s2[g]; }
  }
  __syncthreads();
  if (tid == 0){
    #pragma unroll
    for (int g=0; g<4; ++g){
      double t1 = (sh[0][g*2]+sh[1][g*2]) + (sh[2][g*2]+sh[3][g*2]);
      double t2 = (sh[0][g*2+1]+sh[1][g*2+1]) + (sh[2][g*2+1]+sh[3][g*2+1]);
      int pi = (b*4+g)*nsplit + split;
      part[pi*2] = t1; part[pi*2+1] = t2;
    }
  }
}

__global__ __launch_bounds__(128) void statsred_kernel(const double* __restrict__ part,
    int nsplit, double cnt, float* __restrict__ stats)
{
  int t = threadIdx.x;
  if (t >= BB*4) return;
  double s1=0.0, s2=0.0;
  for (int i=0;i<nsplit;i++){ s1 += part[(t*nsplit+i)*2]; s2 += part[(t*nsplit+i)*2+1]; }
  double mean = s1/cnt;
  double var = s2/cnt - mean*mean;
  double rstd = 1.0 / sqrt(var + 1e-5);
  stats[t*2] = (float)mean;
  stats[t*2+1] = (float)rstd;
}

// ---------------- final pass ----------------
template<int O>
__global__ __launch_bounds__(256) void final_kernel(const float* __restrict__ A,
    const float* __restrict__ Bq, const int* __restrict__ idx,
    const float* __restrict__ stats, const float* __restrict__ gamma,
    const float* __restrict__ beta, float* __restrict__ fout, int Nq, int Nk)
{
  constexpr int LO = ilog2c(O);
  constexpr int LO4 = ilog2c(O/4);
  int b = blockIdx.y;
  int t = blockIdx.x*256 + threadIdx.x;
  if (t >= Nq*O) return;
  int o = t & (O-1);
  int q = t >> LO;
  int g = o >> LO4;
  float mu   = stats[(b*4+g)*2];
  float rstd = stats[(b*4+g)*2+1];
  float gam = gamma[o], bet = beta[o];
  float bq = Bq[(b*Nq+q)*O + o];
  const int* ip = idx + (b*Nq+q)*KNB;
  float m = -__builtin_inff();
  #pragma unroll
  for (int kk=0;kk<KNB;kk++){
    int j = ip[kk];
    float y = A[(b*Nk+j)*O + o] + bq;
    float yn = __fmul_rn(__fsub_rn(y, mu), rstd);
    float yv = __fadd_rn(__fmul_rn(yn, gam), bet);
    float l = yv >= 0.f ? yv : 0.2f*yv;
    m = fmaxf(m, l);
  }
  fout[(b*Nq+q)*O + o] = m;
}

// ---------------- gathers --------------------------------
template<int C>
__global__ __launch_bounds__(256) void gather_kernel(const int* __restrict__ fidx,
    const float* __restrict__ pts, const float* __restrict__ fin,
    float* __restrict__ cq, float* __restrict__ fq, int Nin, int Nout)
{
  int gid = blockIdx.x*256 + threadIdx.x;
  if (gid >= BB*Nout) return;
  int b = gid / Nout;
  int i = gid - b*Nout;
  int src = fidx[b*Nout + i];
  #pragma unroll
  for (int c=0;c<3;c++) cq[gid*3+c] = pts[(b*Nin+src)*3+c];
  #pragma unroll
  for (int c=0;c<C;c++) fq[gid*C+c] = fin[(b*Nin+src)*C+c];
}

__global__ __launch_bounds__(256) void gatherc_kernel(const int* __restrict__ fidx,
    const float* __restrict__ pts, float* __restrict__ cq, int Nin, int Nout)
{
  int gid = blockIdx.x*256 + threadIdx.x;
  if (gid >= BB*Nout) return;
  int b = gid / Nout;
  int i = gid - b*Nout;
  int src = fidx[b*Nout + i];
  #pragma unroll
  for (int c=0;c<3;c++) cq[gid*3+c] = pts[(b*Nin+src)*3+c];
}

template<int C>
__global__ __launch_bounds__(256) void gatherf_kernel(const int* __restrict__ fidx,
    const float* __restrict__ fin, float* __restrict__ fq, int Nin, int Nout)
{
  int gid = blockIdx.x*256 + threadIdx.x;
  if (gid >= BB*Nout) return;
  int b = gid / Nout;
  int i = gid - b*Nout;
  int src = fidx[b*Nout + i];
  #pragma unroll
  for (int c=0;c<C;c++) fq[gid*C+c] = fin[(b*Nin+src)*C+c];
}

extern "C" void kernel_launch(void* const* d_in, const int* in_sizes, int n_in,
                              void* d_out, int out_size, void* d_ws, size_t ws_size,
                              hipStream_t stream)
{
  (void)in_sizes; (void)n_in; (void)out_size; (void)ws_size;
  const float* x    = (const float*)d_in[0];
  const float* w_in = (const float*)d_in[1];
  const float* b_in = (const float*)d_in[2];
  const float* w1 = (const float*)d_in[3];
  const float* g1 = (const float*)d_in[4];
  const float* be1= (const float*)d_in[5];
  const float* w2 = (const float*)d_in[6];
  const float* g2 = (const float*)d_in[7];
  const float* be2= (const float*)d_in[8];
  const float* w3 = (const float*)d_in[9];
  const float* g3 = (const float*)d_in[10];
  const float* be3= (const float*)d_in[11];
  const float* w4 = (const float*)d_in[12];
  const float* g4 = (const float*)d_in[13];
  const float* be4= (const float*)d_in[14];

  float* out = (float*)d_out;
  float* coor_out = out;                    // (32,128,3)
  float* f_out = out + BB*128*3;            // (32,128,256)

  char* ws = (char*)d_ws;
  size_t off = 0;
  auto alloc = [&](size_t bytes)->void*{ void* p = ws + off; off += (bytes + 255) & ~(size_t)255; return p; };

  // ---- persistent buffers (~41.5 MB) ----
  float* f0     = (float*)alloc((size_t)BB*2048*8*4);
  int*   idx1   = (int*)  alloc((size_t)BB*2048*16*4);
  float* f1     = (float*)alloc((size_t)BB*2048*32*4);
  double* part  = (double*)alloc((size_t)BB*4*8*2*8);
  float* statsv = (float*)alloc((size_t)BB*4*2*4);
  int*   fidx0  = (int*)  alloc((size_t)BB*512*4);
  float* coorq1 = (float*)alloc((size_t)BB*512*3*4);
  float* fq1    = (float*)alloc((size_t)BB*512*32*4);
  int*   idx2   = (int*)  alloc((size_t)BB*512*16*4);
  float* f2     = (float*)alloc((size_t)BB*512*64*4);
  int*   idx3   = (int*)  alloc((size_t)BB*512*16*4);
  float* f3     = (float*)alloc((size_t)BB*512*64*4);
  int*   fidx1  = (int*)  alloc((size_t)BB*128*4);
  float* fq2    = (float*)alloc((size_t)BB*128*64*4);
  int*   idx4   = (int*)  alloc((size_t)BB*128*16*4);
  // stage 2/3/4 kNN partials
  float* pd2          = (float*)alloc((size_t)BB*512*8*KNB*4);   // 8 MB
  unsigned char* pi2  = (unsigned char*)alloc((size_t)BB*512*8*KNB); // 2 MB
  float* pd3          = (float*)alloc((size_t)BB*512*2*KNB*4);   // 2 MB
  unsigned char* pi3  = (unsigned char*)alloc((size_t)BB*512*2*KNB); // 0.5 MB
  float* pd4          = (float*)alloc((size_t)BB*128*2*KNB*4);   // 0.5 MB
  unsigned char* pi4  = (unsigned char*)alloc((size_t)BB*128*2*KNB); // 0.125 MB

  // ---- union scratch region (48 MB): stage-1 kNN partials alias A/B buffers.
  char* U = (char*)alloc((size_t)48<<20);
  float* pd1         = (float*)U;                              // 32 MiB
  unsigned char* pi1 = (unsigned char*)(U + ((size_t)34<<20)); // 8 MiB
  float* A  = (float*)U;                                       // max 16 MiB
  float* Bq = (float*)(U + ((size_t)20<<20));                  // max 4 MiB

  auto cdiv = [](int a, int b){ return (a+b-1)/b; };

  // ==== fps0 standalone (single-wave/batch), then knn1|proj throughput kernel ====
  fps_sw32_kernel<<<BB,64,0,stream>>>(x, 512, fidx0);
  fused1_kernel<<<2304,256,0,stream>>>(x, w_in, b_in, f0, pd1, pi1);

  // ---- stage 1 compute ----
  knn_merge_kernel<<<cdiv(BB*2048,256),256,0,stream>>>(pd1, pi1, 2048, 8, idx1);
  gemv_kernel<8,32,false><<<cdiv(BB*2048*4,256),256,0,stream>>>(f0, w1, A, 2048);
  gemv_kernel<8,32,true ><<<cdiv(BB*2048*4,256),256,0,stream>>>(f0, w1, Bq, 2048);
  stats2_kernel<32><<<dim3(BB,8),256,0,stream>>>(A, Bq, idx1, 2048, 2048, part);
  statsred_kernel<<<1,128,0,stream>>>(part, 8, 8.0*2048*16, statsv);
  final_kernel<32><<<dim3(cdiv(2048*32,256),BB),256,0,stream>>>(A, Bq, idx1, statsv, g1, be1, f1, 2048, 2048);

  // ---- gather at fps0 indices ----
  gather_kernel<32><<<cdiv(BB*512,256),256,0,stream>>>(fidx0, x, f1, coorq1, fq1, 2048, 512);

  // ==== fps1 standalone, then knn2|knn3 throughput kernel ====
  fps_sw8_kernel<<<BB,64,0,stream>>>(coorq1, 128, fidx1);
  fused2_kernel<<<640,256,0,stream>>>(coorq1, x, pd2, pi2, pd3, pi3);

  knn_merge_kernel<<<cdiv(BB*512,256),256,0,stream>>>(pd2, pi2, 512, 8, idx2);
  knn_merge_kernel<<<cdiv(BB*512,256),256,0,stream>>>(pd3, pi3, 512, 2, idx3);

  // ---- stage-4 kNN early (needs only fidx1 + coorq1) ----
  gatherc_kernel<<<cdiv(BB*128,256),256,0,stream>>>(fidx1, coorq1, coor_out, 512, 128);
  knn_part_kernel<<<dim3(BB,1,2),256,0,stream>>>(coor_out, coorq1, 128, 512, pd4, pi4);
  knn_merge_kernel<<<cdiv(BB*128,256),256,0,stream>>>(pd4, pi4, 128, 2, idx4);

  // ---- stage 2 compute ----
  gemv_kernel<32,64,false><<<cdiv(BB*2048*8,256),256,0,stream>>>(f1, w2, A, 2048);
  gemv_kernel<32,64,true ><<<cdiv(BB*512*8,256),256,0,stream>>>(fq1, w2, Bq, 512);
  stats2_kernel<64><<<dim3(BB,8),256,0,stream>>>(A, Bq, idx2, 512, 2048, part);
  statsred_kernel<<<1,128,0,stream>>>(part, 8, 16.0*512*16, statsv);
  final_kernel<64><<<dim3(cdiv(512*64,256),BB),256,0,stream>>>(A, Bq, idx2, statsv, g2, be2, f2, 512, 2048);

  // ---- stage 3 compute ----
  gemv_kernel<64,64,false><<<cdiv(BB*512*8,256),256,0,stream>>>(f2, w3, A, 512);
  gemv_kernel<64,64,true ><<<cdiv(BB*512*8,256),256,0,stream>>>(f2, w3, Bq, 512);
  stats2_kernel<64><<<dim3(BB,8),256,0,stream>>>(A, Bq, idx3, 512, 512, part);
  statsred_kernel<<<1,128,0,stream>>>(part, 8, 16.0*512*16, statsv);
  final_kernel<64><<<dim3(cdiv(512*64,256),BB),256,0,stream>>>(A, Bq, idx3, statsv, g3, be3, f3, 512, 512);

  // ---- stage 4 compute ----
  gatherf_kernel<64><<<cdiv(BB*128,256),256,0,stream>>>(fidx1, f3, fq2, 512, 128);
  gemv_kernel<64,256,false><<<cdiv(BB*512*32,256),256,0,stream>>>(f3, w4, A, 512);
  gemv_kernel<64,256,true ><<<cdiv(BB*128*32,256),256,0,stream>>>(fq2, w4, Bq, 128);
  stats2_kernel<256><<<dim3(BB,8),256,0,stream>>>(A, Bq, idx4, 128, 512, part);
  statsred_kernel<<<1,128,0,stream>>>(part, 8, 64.0*128*16, statsv);
  final_kernel<256><<<dim3(cdiv(128*256,256),BB),256,0,stream>>>(A, Bq, idx4, statsv, g4, be4, f_out, 128, 512);
}

// Round 15
// 1336.965 us; speedup vs baseline: 1.3434x; 1.3434x over previous
//
#include <hip/hip_runtime.h>

#define BB 32
#define NPTS0 2048
#define KNB 16
#define KC 256   // key-chunk size for two-pass kNN

constexpr int ilog2c(int n){ int l=0; while(n>1){ n>>=1; ++l; } return l; }

static __device__ __forceinline__ float sq3(float a, float b, float c){
  return __fadd_rn(__fadd_rn(__fmul_rn(a,a),__fmul_rn(b,b)),__fmul_rn(c,c));
}

// DPP helpers: templated so dpp_ctrl/row_mask are integer constant expressions.
template<int CTRL, int RM>
static __device__ __forceinline__ float dpp_maxf(float v){
  int s = __builtin_amdgcn_update_dpp(__float_as_int(v), __float_as_int(v), CTRL, RM, 0xF, false);
  return fmaxf(v, __int_as_float(s));
}
template<int CTRL, int RM>
static __device__ __forceinline__ unsigned dpp_minu(unsigned v){
  unsigned s = (unsigned)__builtin_amdgcn_update_dpp((int)v, (int)v, CTRL, RM, 0xF, false);
  return s < v ? s : v;
}

// ---------------- proj body ----------------
static __device__ __forceinline__ void proj_body(const float* __restrict__ x,
    const float* __restrict__ w, const float* __restrict__ bias, float* __restrict__ f0,
    int blk)
{
  int gid = blk*256 + threadIdx.x;
  if (gid >= BB*NPTS0) return;
  float x0 = x[gid*3+0], x1 = x[gid*3+1], x2 = x[gid*3+2];
  #pragma unroll
  for (int o = 0; o < 8; ++o){
    float acc = __fmul_rn(w[o*3+0], x0);
    acc = __fmaf_rn(w[o*3+1], x1, acc);
    acc = __fmaf_rn(w[o*3+2], x2, acc);
    f0[gid*8+o] = __fadd_rn(acc, bias[o]);
  }
}

// ---------------- NAMED-SCALAR top-16 machinery (registers, no allocas) ------
#define KDECL(I) float th##I = __builtin_inff(); int ti##I = 0;
#define KINS(I,J) if (th##I < th##J){ float tv=th##I; th##I=th##J; th##J=tv; \
                                      int tj=ti##I; ti##I=ti##J; ti##J=tj; }
#define KCASCADE KINS(15,14) KINS(14,13) KINS(13,12) KINS(12,11) KINS(11,10) \
  KINS(10,9) KINS(9,8) KINS(8,7) KINS(7,6) KINS(6,5) KINS(5,4) KINS(4,3) \
  KINS(3,2) KINS(2,1) KINS(1,0)
#define KST(I) pd[base+I] = th##I; pi[base+I] = (unsigned char)ti##I;
#define MST(I) oidx[obase+I] = ti##I;

static __device__ __forceinline__ void knn_part_body(const float* __restrict__ qpts,
    const float* __restrict__ kpts, int Nq, int Nk, int nkc,
    float* __restrict__ pd, unsigned char* __restrict__ pi,
    int b, int qcb, int kc, float4* kk4)
{
  int tid = threadIdx.x;
  {
    int j = kc*KC + tid;                 // Nk is always a multiple of 256
    float a = kpts[(b*Nk+j)*3+0];
    float c = kpts[(b*Nk+j)*3+1];
    float d = kpts[(b*Nk+j)*3+2];
    kk4[tid] = make_float4(a, c, d, sq3(a,c,d));
  }
  __syncthreads();
  int q = qcb*256 + tid;
  if (q >= Nq) return;
  float qx = qpts[(b*Nq+q)*3+0], qy = qpts[(b*Nq+q)*3+1], qz = qpts[(b*Nq+q)*3+2];
  float qq = sq3(qx,qy,qz);
  KDECL(0) KDECL(1) KDECL(2) KDECL(3) KDECL(4) KDECL(5) KDECL(6) KDECL(7)
  KDECL(8) KDECL(9) KDECL(10) KDECL(11) KDECL(12) KDECL(13) KDECL(14) KDECL(15)
  for (int j=0;j<KC;j++){
    float4 k4 = kk4[j];
    float dot = __fmul_rn(qx,k4.x);
    dot = __fmaf_rn(qy,k4.y,dot);
    dot = __fmaf_rn(qz,k4.z,dot);
    float d = __fadd_rn(__fsub_rn(qq, __fmul_rn(2.0f,dot)), k4.w);
    if (d < th15){                        // strict <: equal dist keeps earlier index
      th15 = d; ti15 = j;
      KCASCADE
    }
  }
  size_t base = ((size_t)(b*Nq+q)*nkc + kc)*KNB;
  KST(0) KST(1) KST(2) KST(3) KST(4) KST(5) KST(6) KST(7)
  KST(8) KST(9) KST(10) KST(11) KST(12) KST(13) KST(14) KST(15)
}

// Named-scalar merge body (same semantics as array knn_merge: chunks ascending,
// strict-< insert, chunk lists sorted ascending so early break is safe).
static __device__ __forceinline__ void knn_merge_body(const float* __restrict__ pd,
    const unsigned char* __restrict__ pi, int Nq, int nkc, int* __restrict__ oidx,
    int blk)
{
  int gid = blk*256 + threadIdx.x;
  if (gid >= BB*Nq) return;
  KDECL(0) KDECL(1) KDECL(2) KDECL(3) KDECL(4) KDECL(5) KDECL(6) KDECL(7)
  KDECL(8) KDECL(9) KDECL(10) KDECL(11) KDECL(12) KDECL(13) KDECL(14) KDECL(15)
  size_t base = (size_t)gid*nkc*KNB;
  for (int kc=0;kc<nkc;kc++){
    size_t cb = base + (size_t)kc*KNB;
    for (int i=0;i<KNB;i++){
      float d = pd[cb+i];
      if (d >= th15) break;
      int j = kc*KC + (int)pi[cb+i];
      th15 = d; ti15 = j;
      KCASCADE
    }
  }
  int obase = gid*KNB;
  MST(0) MST(1) MST(2) MST(3) MST(4) MST(5) MST(6) MST(7)
  MST(8) MST(9) MST(10) MST(11) MST(12) MST(13) MST(14) MST(15)
}

// ---------------- FPS bodies: 4-wave (R8/R12-proven) + LDS-buffered output ---------
#define FPS_LOAD(T) float px##T, py##T, pz##T, d##T; { int i_=T*256+tid; \
  px##T=P[i_*3+0]; py##T=P[i_*3+1]; pz##T=P[i_*3+2]; \
  float dx_=__fsub_rn(px##T,c0x), dy_=__fsub_rn(py##T,c0y), dz_=__fsub_rn(pz##T,c0z); \
  d##T=sq3(dx_,dy_,dz_); bm=fmaxf(bm,d##T); }
#define FPS_MATCH(T) if (d##T == m_w) ci = (unsigned)(T*256 + tid);
#define FPS_OWN(T) if ((idx_w>>8) == T##u){ cx=px##T; cy=py##T; cz=pz##T; }
#define FPS_UPD(T) { float dx_=__fsub_rn(px##T,sx), dy_=__fsub_rn(py##T,sy), dz_=__fsub_rn(pz##T,sz); \
  float nd_=sq3(dx_,dy_,dz_); d##T=fminf(d##T,nd_); nbm=fmaxf(nbm,d##T); }

#define FPS_REDUCE_AND_PICK \
    float v = bm; \
    v = dpp_maxf<0x111, 0xF>(v); \
    v = dpp_maxf<0x112, 0xF>(v); \
    v = dpp_maxf<0x114, 0xF>(v); \
    v = dpp_maxf<0x118, 0xF>(v); \
    v = dpp_maxf<0x142, 0xA>(v); \
    v = dpp_maxf<0x143, 0xC>(v); \
    float m_w = __int_as_float(__builtin_amdgcn_readlane(__float_as_int(v), 63)); \
    unsigned ci = 0xFFFFFFFFu;

#define FPS_MIN_AND_MERGE \
    ci = dpp_minu<0x111, 0xF>(ci); \
    ci = dpp_minu<0x112, 0xF>(ci); \
    ci = dpp_minu<0x114, 0xF>(ci); \
    ci = dpp_minu<0x118, 0xF>(ci); \
    ci = dpp_minu<0x142, 0xA>(ci); \
    ci = dpp_minu<0x143, 0xC>(ci); \
    unsigned idx_w = (unsigned)__builtin_amdgcn_readlane((int)ci, 63); \
    int par = s & 1;

#define FPS_CROSSWAVE \
    __syncthreads(); \
    float4 q0 = *(const float4*)&swp[par][0][0]; float z0 = swp[par][0][4]; \
    float4 q1 = *(const float4*)&swp[par][1][0]; float z1 = swp[par][1][4]; \
    float4 q2 = *(const float4*)&swp[par][2][0]; float z2 = swp[par][2][4]; \
    float4 q3 = *(const float4*)&swp[par][3][0]; float z3 = swp[par][3][4]; \
    float mm = q0.x; unsigned mi = __float_as_uint(q0.y); \
    float sx = q0.z, sy = q0.w, sz = z0; \
    if (q1.x > mm || (q1.x == mm && __float_as_uint(q1.y) < mi)){ \
      mm = q1.x; mi = __float_as_uint(q1.y); sx = q1.z; sy = q1.w; sz = z1; } \
    if (q2.x > mm || (q2.x == mm && __float_as_uint(q2.y) < mi)){ \
      mm = q2.x; mi = __float_as_uint(q2.y); sx = q2.z; sy = q2.w; sz = z2; } \
    if (q3.x > mm || (q3.x == mm && __float_as_uint(q3.y) < mi)){ \
      mm = q3.x; mi = __float_as_uint(q3.y); sx = q3.z; sy = q3.w; sz = z3; } \
    if (tid == 0) oibuf[s] = (int)mi;

static __device__ __forceinline__ void fps8_body(const float* __restrict__ pts,
    int S, int* __restrict__ oidx, int b, char* smraw)
{
  float (*swp)[4][8] = reinterpret_cast<float(*)[4][8]>(smraw);  // [2][4][8] = 256B
  int* oibuf = reinterpret_cast<int*>(smraw + 256);              // S*4 bytes
  int tid = threadIdx.x, wid = tid >> 6;
  const float* P = pts + (size_t)b*2048*3;
  float c0x = P[0], c0y = P[1], c0z = P[2];
  float bm = -1.0f;
  FPS_LOAD(0) FPS_LOAD(1) FPS_LOAD(2) FPS_LOAD(3)
  FPS_LOAD(4) FPS_LOAD(5) FPS_LOAD(6) FPS_LOAD(7)
  if (tid == 0) oibuf[0] = 0;
  for (int s=1; s<S; ++s){
    FPS_REDUCE_AND_PICK
    FPS_MATCH(7) FPS_MATCH(6) FPS_MATCH(5) FPS_MATCH(4)
    FPS_MATCH(3) FPS_MATCH(2) FPS_MATCH(1) FPS_MATCH(0)
    FPS_MIN_AND_MERGE
    if (tid == (int)(idx_w & 255u)){       // each wave's winner lane writes its slot
      float cx = px0, cy = py0, cz = pz0;
      FPS_OWN(1) FPS_OWN(2) FPS_OWN(3) FPS_OWN(4) FPS_OWN(5) FPS_OWN(6) FPS_OWN(7)
      float4* wp = (float4*)&swp[par][wid][0];
      *wp = make_float4(m_w, __uint_as_float(idx_w), cx, cy);
      swp[par][wid][4] = cz;
    }
    FPS_CROSSWAVE
    float nbm = -1.0f;
    FPS_UPD(0) FPS_UPD(1) FPS_UPD(2) FPS_UPD(3)
    FPS_UPD(4) FPS_UPD(5) FPS_UPD(6) FPS_UPD(7)
    bm = nbm;
  }
  __syncthreads();
  for (int s2 = tid; s2 < S; s2 += 256) oidx[b*S + s2] = oibuf[s2];
}

static __device__ __forceinline__ void fps2_body(const float* __restrict__ pts,
    int S, int* __restrict__ oidx, int b, char* smraw)
{
  float (*swp)[4][8] = reinterpret_cast<float(*)[4][8]>(smraw);
  int* oibuf = reinterpret_cast<int*>(smraw + 256);
  int tid = threadIdx.x, wid = tid >> 6;
  const float* P = pts + (size_t)b*512*3;
  float c0x = P[0], c0y = P[1], c0z = P[2];
  float bm = -1.0f;
  FPS_LOAD(0) FPS_LOAD(1)
  if (tid == 0) oibuf[0] = 0;
  for (int s=1; s<S; ++s){
    FPS_REDUCE_AND_PICK
    FPS_MATCH(1) FPS_MATCH(0)
    FPS_MIN_AND_MERGE
    if (tid == (int)(idx_w & 255u)){
      float cx = px0, cy = py0, cz = pz0;
      FPS_OWN(1)
      float4* wp = (float4*)&swp[par][wid][0];
      *wp = make_float4(m_w, __uint_as_float(idx_w), cx, cy);
      swp[par][wid][4] = cz;
    }
    FPS_CROSSWAVE
    float nbm = -1.0f;
    FPS_UPD(0) FPS_UPD(1)
    bm = nbm;
  }
  __syncthreads();
  for (int s2 = tid; s2 < S; s2 += 256) oidx[b*S + s2] = oibuf[s2];
}

// ---------------- fused launch 1: fps0 (32) | knn1_part (2048) | proj (256) --------
__global__ __launch_bounds__(256) void fused1_kernel(const float* __restrict__ x,
    const float* __restrict__ w_in, const float* __restrict__ b_in,
    float* __restrict__ f0, float* __restrict__ pd1, unsigned char* __restrict__ pi1,
    int* __restrict__ fidx0)
{
  __shared__ __align__(16) char sm[4096];
  int bid = blockIdx.x;
  if (bid < 32){
    __builtin_amdgcn_s_setprio(3);
    fps8_body(x, 512, fidx0, bid, sm);
  } else if (bid < 32+2048){
    int r = bid - 32;
    int b = r & 31; int rest = r >> 5;
    knn_part_body(x, x, 2048, 2048, 8, pd1, pi1, b, rest & 7, rest >> 3, (float4*)sm);
  } else {
    proj_body(x, w_in, b_in, f0, bid - 2080);
  }
}

// ---------------- fused launch 2: fps1 (32) | knn2 (512) | knn3 (128) | merge1 (256)
__global__ __launch_bounds__(256) void fused2_kernel(const float* __restrict__ coorq1,
    const float* __restrict__ x,
    float* __restrict__ pd2, unsigned char* __restrict__ pi2,
    float* __restrict__ pd3, unsigned char* __restrict__ pi3,
    int* __restrict__ fidx1,
    const float* __restrict__ pd1, const unsigned char* __restrict__ pi1,
    int* __restrict__ idx1)
{
  __shared__ __align__(16) char sm[4096];
  int bid = blockIdx.x;
  if (bid < 32){
    __builtin_amdgcn_s_setprio(3);
    fps2_body(coorq1, 128, fidx1, bid, sm);
  } else if (bid < 32+512){
    int r = bid - 32;
    int b = r & 31; int rest = r >> 5;
    knn_part_body(coorq1, x, 512, 2048, 8, pd2, pi2, b, rest & 1, rest >> 1, (float4*)sm);
  } else if (bid < 32+512+128){
    int r = bid - 544;
    int b = r & 31; int rest = r >> 5;
    knn_part_body(coorq1, coorq1, 512, 512, 2, pd3, pi3, b, rest & 1, rest >> 1, (float4*)sm);
  } else {
    knn_merge_body(pd1, pi1, 2048, 8, idx1, bid - 672);
  }
}

// ---------------- standalone knn_part (stage 4) ----------------
__global__ __launch_bounds__(256) void knn_part_kernel(const float* __restrict__ qpts,
    const float* __restrict__ kpts, int Nq, int Nk,
    float* __restrict__ pd, unsigned char* __restrict__ pi)
{
  __shared__ __align__(16) float4 kk4[KC];
  knn_part_body(qpts, kpts, Nq, Nk, gridDim.z, pd, pi,
                blockIdx.x, blockIdx.y, blockIdx.z, kk4);
}

// ---------------- standalone merge ----------------
__global__ __launch_bounds__(256) void knn_merge_kernel(const float* __restrict__ pd,
    const unsigned char* __restrict__ pi, int Nq, int nkc, int* __restrict__ oidx)
{
  knn_merge_body(pd, pi, Nq, nkc, oidx, blockIdx.x);
}

// ---------------- per-point GEMV body + dual kernel (A and B in one launch) --------
template<int C, int O, bool DIFF>
static __device__ __forceinline__ void gemv_body(const float* __restrict__ fin,
    const float* __restrict__ W, float* __restrict__ out, int Npts, int blk)
{
  constexpr int NT = O/8;
  constexpr int LNT = ilog2c(NT);
  int gid = blk*256 + threadIdx.x;
  if (gid >= BB*Npts*NT) return;
  int tile = gid & (NT-1);
  int pn = gid >> LNT;
  const float* frow = fin + pn*C;
  float f[C];
  #pragma unroll
  for (int c=0;c<C;c++) f[c] = frow[c];
  float acc[8];
  const float* wbase = W + (tile*8)*(2*C);
  #pragma unroll
  for (int oo=0;oo<8;oo++){
    const float* wrow = wbase + oo*(2*C);
    float a = 0.f;
    #pragma unroll
    for (int c=0;c<C;c++){
      float wv = DIFF ? __fsub_rn(wrow[C+c], wrow[c]) : wrow[c];
      a = __fmaf_rn(wv, f[c], a);
    }
    acc[oo] = a;
  }
  float* orow = out + pn*O + tile*8;
  #pragma unroll
  for (int oo=0;oo<8;oo++) orow[oo] = acc[oo];
}

template<int C, int O>
__global__ __launch_bounds__(256) void gemv_dual_kernel(const float* __restrict__ finA,
    const float* __restrict__ finB, const float* __restrict__ W,
    float* __restrict__ outA, float* __restrict__ outB,
    int NptsA, int NptsB, int nAblk)
{
  int bid = blockIdx.x;
  if (bid < nAblk) gemv_body<C,O,false>(finA, W, outA, NptsA, bid);
  else             gemv_body<C,O,true >(finB, W, outB, NptsB, bid - nAblk);
}

// ---------------- GN stats pass v2: one thread per (q,kk) pair ----------------
template<int O>
__global__ __launch_bounds__(256) void stats2_kernel(const float* __restrict__ A,
    const float* __restrict__ Bq, const int* __restrict__ idx, int Nq, int Nk,
    double* __restrict__ part)
{
  constexpr int O4 = O/4;
  int b = blockIdx.x, split = blockIdx.y, nsplit = gridDim.y;
  int qlen = Nq / nsplit, q0 = split*qlen;
  int tid = threadIdx.x;
  int pairs = qlen * KNB;
  double s1[4] = {0.0,0.0,0.0,0.0};
  double s2[4] = {0.0,0.0,0.0,0.0};
  for (int p = tid; p < pairs; p += 256){
    int q = q0 + (p >> 4);
    int kk = p & 15;
    int j = idx[(b*Nq+q)*KNB + kk];
    const float* arow = A + (size_t)(b*Nk+j)*O;
    const float* brow = Bq + (size_t)(b*Nq+q)*O;
    #pragma unroll
    for (int g=0; g<4; ++g){
      float cs1 = 0.f, cs2 = 0.f;
      #pragma unroll
      for (int c=0; c<O4; c+=4){
        float4 a4 = *(const float4*)(arow + g*O4 + c);
        float4 b4 = *(const float4*)(brow + g*O4 + c);
        float y0 = a4.x+b4.x, y1 = a4.y+b4.y, y2 = a4.z+b4.z, y3 = a4.w+b4.w;
        cs1 += ((y0+y1)+(y2+y3));
        cs2 = fmaf(y0,y0,cs2); cs2 = fmaf(y1,y1,cs2);
        cs2 = fmaf(y2,y2,cs2); cs2 = fmaf(y3,y3,cs2);
      }
      s1[g] += (double)cs1;
      s2[g] += (double)cs2;
    }
  }
  #pragma unroll
  for (int m=32;m>0;m>>=1){
    #pragma unroll
    for (int g=0; g<4; ++g){
      s1[g] += __shfl_down(s1[g], m);
      s2[g] += __shfl_down(s2[g], m);
    }
  }
  __shared__ double sh[4][8];
  int lane = tid & 63, w = tid >> 6;
  if (lane == 0){
    #pragma unroll
    for (int g=0; g<4; ++g){ sh[w][g*2] = s1[g]; sh[w][g*2+1] = s2[g]; }
  }
  __syncthreads();
  if (tid == 0){
    #pragma unroll
    for (int g=0; g<4; ++g){
      double t1 = (sh[0][g*2]+sh[1][g*2]) + (sh[2][g*2]+sh[3][g*2]);
      double t2 = (sh[0][g*2+1]+sh[1][g*2+1]) + (sh[2][g*2+1]+sh[3][g*2+1]);
      int pi = (b*4+g)*nsplit + split;
      part[pi*2] = t1; part[pi*2+1] = t2;
    }
  }
}

// ---------------- final pass: inline stats reduce (per-block, bit-identical to the
// old statsred: sequential i-loop in f64), then normalize/gamma/beta/leaky/max -----
template<int O>
__global__ __launch_bounds__(256) void final_kernel(const float* __restrict__ A,
    const float* __restrict__ Bq, const int* __restrict__ idx,
    const double* __restrict__ part, int nsplit, double cnt,
    const float* __restrict__ gamma, const float* __restrict__ beta,
    float* __restrict__ fout, int Nq, int Nk)
{
  constexpr int LO = ilog2c(O);
  constexpr int LO4 = ilog2c(O/4);
  __shared__ float smu[4], srs[4];
  int b = blockIdx.y;
  if (threadIdx.x < 4){
    int g = threadIdx.x;
    int t0 = b*4+g;
    double s1=0.0, s2=0.0;
    for (int i=0;i<nsplit;i++){ s1 += part[(t0*nsplit+i)*2]; s2 += part[(t0*nsplit+i)*2+1]; }
    double mean = s1/cnt;
    double var = s2/cnt - mean*mean;
    double rstd = 1.0 / sqrt(var + 1e-5);
    smu[g] = (float)mean;
    srs[g] = (float)rstd;
  }
  __syncthreads();
  int t = blockIdx.x*256 + threadIdx.x;
  if (t >= Nq*O) return;
  int o = t & (O-1);
  int q = t >> LO;
  int g = o >> LO4;
  float mu   = smu[g];
  float rstd = srs[g];
  float gam = gamma[o], bet = beta[o];
  float bq = Bq[(b*Nq+q)*O + o];
  const int* ip = idx + (b*Nq+q)*KNB;
  float m = -__builtin_inff();
  #pragma unroll
  for (int kk=0;kk<KNB;kk++){
    int j = ip[kk];
    float y = A[(b*Nk+j)*O + o] + bq;
    float yn = __fmul_rn(__fsub_rn(y, mu), rstd);
    float yv = __fadd_rn(__fmul_rn(yn, gam), bet);
    float l = yv >= 0.f ? yv : 0.2f*yv;
    m = fmaxf(m, l);
  }
  fout[(b*Nq+q)*O + o] = m;
}

// ---------------- gathers --------------------------------
__global__ __launch_bounds__(256) void gatherc_kernel(const int* __restrict__ fidx,
    const float* __restrict__ pts, float* __restrict__ cq, int Nin, int Nout)
{
  int gid = blockIdx.x*256 + threadIdx.x;
  if (gid >= BB*Nout) return;
  int b = gid / Nout;
  int i = gid - b*Nout;
  int src = fidx[b*Nout + i];
  #pragma unroll
  for (int c=0;c<3;c++) cq[gid*3+c] = pts[(b*Nin+src)*3+c];
}

template<int C>
__global__ __launch_bounds__(256) void gatherf_kernel(const int* __restrict__ fidx,
    const float* __restrict__ fin, float* __restrict__ fq, int Nin, int Nout)
{
  int gid = blockIdx.x*256 + threadIdx.x;
  if (gid >= BB*Nout) return;
  int b = gid / Nout;
  int i = gid - b*Nout;
  int src = fidx[b*Nout + i];
  #pragma unroll
  for (int c=0;c<C;c++) fq[gid*C+c] = fin[(b*Nin+src)*C+c];
}

extern "C" void kernel_launch(void* const* d_in, const int* in_sizes, int n_in,
                              void* d_out, int out_size, void* d_ws, size_t ws_size,
                              hipStream_t stream)
{
  (void)in_sizes; (void)n_in; (void)out_size; (void)ws_size;
  const float* x    = (const float*)d_in[0];
  const float* w_in = (const float*)d_in[1];
  const float* b_in = (const float*)d_in[2];
  const float* w1 = (const float*)d_in[3];
  const float* g1 = (const float*)d_in[4];
  const float* be1= (const float*)d_in[5];
  const float* w2 = (const float*)d_in[6];
  const float* g2 = (const float*)d_in[7];
  const float* be2= (const float*)d_in[8];
  const float* w3 = (const float*)d_in[9];
  const float* g3 = (const float*)d_in[10];
  const float* be3= (const float*)d_in[11];
  const float* w4 = (const float*)d_in[12];
  const float* g4 = (const float*)d_in[13];
  const float* be4= (const float*)d_in[14];

  float* out = (float*)d_out;
  float* coor_out = out;                    // (32,128,3)
  float* f_out = out + BB*128*3;            // (32,128,256)

  char* ws = (char*)d_ws;
  size_t off = 0;
  auto alloc = [&](size_t bytes)->void*{ void* p = ws + off; off += (bytes + 255) & ~(size_t)255; return p; };

  // ---- persistent buffers ----
  float* f0     = (float*)alloc((size_t)BB*2048*8*4);
  int*   idx1   = (int*)  alloc((size_t)BB*2048*16*4);
  float* f1     = (float*)alloc((size_t)BB*2048*32*4);
  double* part  = (double*)alloc((size_t)BB*4*8*2*8);
  int*   fidx0  = (int*)  alloc((size_t)BB*512*4);
  float* coorq1 = (float*)alloc((size_t)BB*512*3*4);
  float* fq1    = (float*)alloc((size_t)BB*512*32*4);
  int*   idx2   = (int*)  alloc((size_t)BB*512*16*4);
  float* f2     = (float*)alloc((size_t)BB*512*64*4);
  int*   idx3   = (int*)  alloc((size_t)BB*512*16*4);
  float* f3     = (float*)alloc((size_t)BB*512*64*4);
  int*   fidx1  = (int*)  alloc((size_t)BB*128*4);
  float* fq2    = (float*)alloc((size_t)BB*128*64*4);
  int*   idx4   = (int*)  alloc((size_t)BB*128*16*4);
  // stage 2/3/4 kNN partials
  float* pd2          = (float*)alloc((size_t)BB*512*8*KNB*4);
  unsigned char* pi2  = (unsigned char*)alloc((size_t)BB*512*8*KNB);
  float* pd3          = (float*)alloc((size_t)BB*512*2*KNB*4);
  unsigned char* pi3  = (unsigned char*)alloc((size_t)BB*512*2*KNB);
  float* pd4          = (float*)alloc((size_t)BB*128*2*KNB*4);
  unsigned char* pi4  = (unsigned char*)alloc((size_t)BB*128*2*KNB);

  // ---- union scratch region (48 MB): stage-1 kNN partials alias A/B buffers.
  // merge1 (inside fused2) reads pd1/pi1; gemv_dual writes A/Bq strictly AFTER
  // fused2 completes (stream order) -> no overlap in time.
  char* U = (char*)alloc((size_t)48<<20);
  float* pd1         = (float*)U;                              // 32 MiB
  unsigned char* pi1 = (unsigned char*)(U + ((size_t)34<<20)); // 8 MiB
  float* A  = (float*)U;                                       // max 16 MiB
  float* Bq = (float*)(U + ((size_t)20<<20));                  // max 4 MiB

  auto cdiv = [](int a, int b){ return (a+b-1)/b; };

  // ==== F1: fps0 | knn1_part | proj ====
  fused1_kernel<<<2336,256,0,stream>>>(x, w_in, b_in, f0, pd1, pi1, fidx0);

  // coords for queries of stages 2/3 (needs only fidx0 + x)
  gatherc_kernel<<<cdiv(BB*512,256),256,0,stream>>>(fidx0, x, coorq1, 2048, 512);

  // ==== F2: fps1 | knn2 | knn3 | merge1 (merge1 hidden under fps1 chain) ====
  fused2_kernel<<<928,256,0,stream>>>(coorq1, x, pd2, pi2, pd3, pi3, fidx1,
                                      pd1, pi1, idx1);

  // ---- stage 1 compute ----
  gemv_dual_kernel<8,32><<<2048,256,0,stream>>>(f0, f0, w1, A, Bq, 2048, 2048, 1024);
  stats2_kernel<32><<<dim3(BB,8),256,0,stream>>>(A, Bq, idx1, 2048, 2048, part);
  final_kernel<32><<<dim3(cdiv(2048*32,256),BB),256,0,stream>>>(A, Bq, idx1, part, 8,
      8.0*2048*16, g1, be1, f1, 2048, 2048);
  gatherf_kernel<32><<<cdiv(BB*512,256),256,0,stream>>>(fidx0, f1, fq1, 2048, 512);

  // ---- merges for stages 2/3 ----
  knn_merge_kernel<<<cdiv(BB*512,256),256,0,stream>>>(pd2, pi2, 512, 8, idx2);
  knn_merge_kernel<<<cdiv(BB*512,256),256,0,stream>>>(pd3, pi3, 512, 2, idx3);

  // ---- stage-4 kNN early (needs only fidx1 + coorq1) ----
  gatherc_kernel<<<cdiv(BB*128,256),256,0,stream>>>(fidx1, coorq1, coor_out, 512, 128);
  knn_part_kernel<<<dim3(BB,1,2),256,0,stream>>>(coor_out, coorq1, 128, 512, pd4, pi4);
  knn_merge_kernel<<<cdiv(BB*128,256),256,0,stream>>>(pd4, pi4, 128, 2, idx4);

  // ---- stage 2 compute ----
  gemv_dual_kernel<32,64><<<2560,256,0,stream>>>(f1, fq1, w2, A, Bq, 2048, 512, 2048);
  stats2_kernel<64><<<dim3(BB,8),256,0,stream>>>(A, Bq, idx2, 512, 2048, part);
  final_kernel<64><<<dim3(cdiv(512*64,256),BB),256,0,stream>>>(A, Bq, idx2, part, 8,
      16.0*512*16, g2, be2, f2, 512, 2048);

  // ---- stage 3 compute ----
  gemv_dual_kernel<64,64><<<1024,256,0,stream>>>(f2, f2, w3, A, Bq, 512, 512, 512);
  stats2_kernel<64><<<dim3(BB,8),256,0,stream>>>(A, Bq, idx3, 512, 512, part);
  final_kernel<64><<<dim3(cdiv(512*64,256),BB),256,0,stream>>>(A, Bq, idx3, part, 8,
      16.0*512*16, g3, be3, f3, 512, 512);

  // ---- stage 4 compute ----
  gatherf_kernel<64><<<cdiv(BB*128,256),256,0,stream>>>(fidx1, f3, fq2, 512, 128);
  gemv_dual_kernel<64,256><<<2560,256,0,stream>>>(f3, fq2, w4, A, Bq, 512, 128, 2048);
  stats2_kernel<256><<<dim3(BB,8),256,0,stream>>>(A, Bq, idx4, 128, 512, part);
  final_kernel<256><<<dim3(cdiv(128*256,256),BB),256,0,stream>>>(A, Bq, idx4, part, 8,
      64.0*128*16, g4, be4, f_out, 128, 512);
}

// Round 16
// 1218.201 us; speedup vs baseline: 1.4743x; 1.0975x over previous
//
#include <hip/hip_runtime.h>

#define BB 32
#define NPTS0 2048
#define KNB 16
#define KC 256

constexpr int ilog2c(int n){ int l=0; while(n>1){ n>>=1; ++l; } return l; }

static __device__ __forceinline__ float sq3(float a, float b, float c){
  return __fadd_rn(__fadd_rn(__fmul_rn(a,a),__fmul_rn(b,b)),__fmul_rn(c,c));
}

template<int CTRL, int RM>
static __device__ __forceinline__ float dpp_maxf(float v){
  int s = __builtin_amdgcn_update_dpp(__float_as_int(v), __float_as_int(v), CTRL, RM, 0xF, false);
  return fmaxf(v, __int_as_float(s));
}
template<int CTRL, int RM>
static __device__ __forceinline__ unsigned dpp_minu(unsigned v){
  unsigned s = (unsigned)__builtin_amdgcn_update_dpp((int)v, (int)v, CTRL, RM, 0xF, false);
  return s < v ? s : v;
}

// ---------------- proj body ----------------
static __device__ __forceinline__ void proj_body(const float* __restrict__ x,
    const float* __restrict__ w, const float* __restrict__ bias, float* __restrict__ f0,
    int blk)
{
  int gid = blk*256 + threadIdx.x;
  if (gid >= BB*NPTS0) return;
  float x0 = x[gid*3+0], x1 = x[gid*3+1], x2 = x[gid*3+2];
  #pragma unroll
  for (int o = 0; o < 8; ++o){
    float acc = __fmul_rn(w[o*3+0], x0);
    acc = __fmaf_rn(w[o*3+1], x1, acc);
    acc = __fmaf_rn(w[o*3+2], x2, acc);
    f0[gid*8+o] = __fadd_rn(acc, bias[o]);
  }
}

// ---------------- NAMED-SCALAR top-16 machinery ----------------
#define KDECL(I) float th##I = __builtin_inff(); int ti##I = 0;
#define KINS(I,J) if (th##I < th##J){ float tv=th##I; th##I=th##J; th##J=tv; \
                                      int tj=ti##I; ti##I=ti##J; ti##J=tj; }
#define KCASCADE KINS(15,14) KINS(14,13) KINS(13,12) KINS(12,11) KINS(11,10) \
  KINS(10,9) KINS(9,8) KINS(8,7) KINS(7,6) KINS(6,5) KINS(5,4) KINS(4,3) \
  KINS(3,2) KINS(2,1) KINS(1,0)
#define KALLDECL KDECL(0) KDECL(1) KDECL(2) KDECL(3) KDECL(4) KDECL(5) KDECL(6) KDECL(7) \
  KDECL(8) KDECL(9) KDECL(10) KDECL(11) KDECL(12) KDECL(13) KDECL(14) KDECL(15)
#define KST(I) pd[base+I] = th##I; pi[base+I] = (unsigned char)ti##I;
#define KST16(I) pd[base+I] = th##I; pi[base+I] = (unsigned short)ti##I;
#define MST(I) oidx[obase+I] = ti##I;

// stage-1 kNN: 512-key chunks, two sequential 256-key LDS tiles, u16 local idx.
// Tiles scanned in ascending index order -> identical tie semantics.
static __device__ __forceinline__ void knn_part512_body(const float* __restrict__ qpts,
    const float* __restrict__ kpts, int Nq, int Nk, int nkc,
    float* __restrict__ pd, unsigned short* __restrict__ pi,
    int b, int qcb, int kc, float4* kk4)
{
  int tid = threadIdx.x;
  int q = qcb*256 + tid;                    // Nq=2048: always valid
  float qx = qpts[(b*Nq+q)*3+0], qy = qpts[(b*Nq+q)*3+1], qz = qpts[(b*Nq+q)*3+2];
  float qq = sq3(qx,qy,qz);
  KALLDECL
  #pragma unroll
  for (int half=0; half<2; ++half){
    __syncthreads();
    {
      int j = kc*512 + half*256 + tid;
      float a = kpts[(b*Nk+j)*3+0];
      float c = kpts[(b*Nk+j)*3+1];
      float dd = kpts[(b*Nk+j)*3+2];
      kk4[tid] = make_float4(a, c, dd, sq3(a,c,dd));
    }
    __syncthreads();
    for (int j=0;j<KC;j++){
      float4 k4 = kk4[j];
      float dot = __fmul_rn(qx,k4.x);
      dot = __fmaf_rn(qy,k4.y,dot);
      dot = __fmaf_rn(qz,k4.z,dot);
      float d = __fadd_rn(__fsub_rn(qq, __fmul_rn(2.0f,dot)), k4.w);
      if (d < th15){
        th15 = d; ti15 = half*256 + j;
        KCASCADE
      }
    }
  }
  size_t base = ((size_t)(b*Nq+q)*nkc + kc)*KNB;
  KST16(0) KST16(1) KST16(2) KST16(3) KST16(4) KST16(5) KST16(6) KST16(7)
  KST16(8) KST16(9) KST16(10) KST16(11) KST16(12) KST16(13) KST16(14) KST16(15)
}

// generic 256-key-chunk kNN, optional indirect queries (qidx/NinQ)
static __device__ __forceinline__ void knn_part_body(const float* __restrict__ qpts,
    const float* __restrict__ kpts, int Nq, int Nk, int nkc,
    float* __restrict__ pd, unsigned char* __restrict__ pi,
    int b, int qcb, int kc, float4* kk4, const int* __restrict__ qidx, int NinQ)
{
  int tid = threadIdx.x;
  {
    int j = kc*KC + tid;
    float a = kpts[(b*Nk+j)*3+0];
    float c = kpts[(b*Nk+j)*3+1];
    float d = kpts[(b*Nk+j)*3+2];
    kk4[tid] = make_float4(a, c, d, sq3(a,c,d));
  }
  __syncthreads();
  int q = qcb*256 + tid;
  if (q >= Nq) return;                      // no barriers after this point
  int qrow = qidx ? (b*NinQ + qidx[b*Nq+q]) : (b*Nq+q);
  float qx = qpts[qrow*3+0], qy = qpts[qrow*3+1], qz = qpts[qrow*3+2];
  float qq = sq3(qx,qy,qz);
  KALLDECL
  for (int j=0;j<KC;j++){
    float4 k4 = kk4[j];
    float dot = __fmul_rn(qx,k4.x);
    dot = __fmaf_rn(qy,k4.y,dot);
    dot = __fmaf_rn(qz,k4.z,dot);
    float d = __fadd_rn(__fsub_rn(qq, __fmul_rn(2.0f,dot)), k4.w);
    if (d < th15){
      th15 = d; ti15 = j;
      KCASCADE
    }
  }
  size_t base = ((size_t)(b*Nq+q)*nkc + kc)*KNB;
  KST(0) KST(1) KST(2) KST(3) KST(4) KST(5) KST(6) KST(7)
  KST(8) KST(9) KST(10) KST(11) KST(12) KST(13) KST(14) KST(15)
}

// merge for 256-key chunks (u8 local idx)
static __device__ __forceinline__ void knn_merge_body(const float* __restrict__ pd,
    const unsigned char* __restrict__ pi, int Nq, int nkc, int* __restrict__ oidx,
    int blk)
{
  int gid = blk*256 + threadIdx.x;
  if (gid >= BB*Nq) return;
  KALLDECL
  size_t base = (size_t)gid*nkc*KNB;
  for (int kc=0;kc<nkc;kc++){
    size_t cb = base + (size_t)kc*KNB;
    for (int i=0;i<KNB;i++){
      float d = pd[cb+i];
      if (d >= th15) break;
      int j = kc*KC + (int)pi[cb+i];
      th15 = d; ti15 = j;
      KCASCADE
    }
  }
  int obase = gid*KNB;
  MST(0) MST(1) MST(2) MST(3) MST(4) MST(5) MST(6) MST(7)
  MST(8) MST(9) MST(10) MST(11) MST(12) MST(13) MST(14) MST(15)
}

// merge for 512-key chunks (u16 local idx)
static __device__ __forceinline__ void knn_merge512_body(const float* __restrict__ pd,
    const unsigned short* __restrict__ pi, int Nq, int nkc, int* __restrict__ oidx,
    int blk)
{
  int gid = blk*256 + threadIdx.x;
  if (gid >= BB*Nq) return;
  KALLDECL
  size_t base = (size_t)gid*nkc*KNB;
  for (int kc=0;kc<nkc;kc++){
    size_t cb = base + (size_t)kc*KNB;
    for (int i=0;i<KNB;i++){
      float d = pd[cb+i];
      if (d >= th15) break;
      int j = kc*512 + (int)pi[cb+i];
      th15 = d; ti15 = j;
      KCASCADE
    }
  }
  int obase = gid*KNB;
  MST(0) MST(1) MST(2) MST(3) MST(4) MST(5) MST(6) MST(7)
  MST(8) MST(9) MST(10) MST(11) MST(12) MST(13) MST(14) MST(15)
}

// ---------------- FPS bodies: 4-wave + LDS-buffered output (R12/R15-proven) --------
#define FPS_LOAD(T) float px##T, py##T, pz##T, d##T; { int i_=T*256+tid; \
  px##T=P[i_*3+0]; py##T=P[i_*3+1]; pz##T=P[i_*3+2]; \
  float dx_=__fsub_rn(px##T,c0x), dy_=__fsub_rn(py##T,c0y), dz_=__fsub_rn(pz##T,c0z); \
  d##T=sq3(dx_,dy_,dz_); bm=fmaxf(bm,d##T); }
#define FPS_MATCH(T) if (d##T == m_w) ci = (unsigned)(T*256 + tid);
#define FPS_OWN(T) if ((idx_w>>8) == T##u){ cx=px##T; cy=py##T; cz=pz##T; }
#define FPS_UPD(T) { float dx_=__fsub_rn(px##T,sx), dy_=__fsub_rn(py##T,sy), dz_=__fsub_rn(pz##T,sz); \
  float nd_=sq3(dx_,dy_,dz_); d##T=fminf(d##T,nd_); nbm=fmaxf(nbm,d##T); }

#define FPS_REDUCE_AND_PICK \
    float v = bm; \
    v = dpp_maxf<0x111, 0xF>(v); \
    v = dpp_maxf<0x112, 0xF>(v); \
    v = dpp_maxf<0x114, 0xF>(v); \
    v = dpp_maxf<0x118, 0xF>(v); \
    v = dpp_maxf<0x142, 0xA>(v); \
    v = dpp_maxf<0x143, 0xC>(v); \
    float m_w = __int_as_float(__builtin_amdgcn_readlane(__float_as_int(v), 63)); \
    unsigned ci = 0xFFFFFFFFu;

#define FPS_MIN_AND_MERGE \
    ci = dpp_minu<0x111, 0xF>(ci); \
    ci = dpp_minu<0x112, 0xF>(ci); \
    ci = dpp_minu<0x114, 0xF>(ci); \
    ci = dpp_minu<0x118, 0xF>(ci); \
    ci = dpp_minu<0x142, 0xA>(ci); \
    ci = dpp_minu<0x143, 0xC>(ci); \
    unsigned idx_w = (unsigned)__builtin_amdgcn_readlane((int)ci, 63); \
    int par = s & 1;

#define FPS_CROSSWAVE \
    __syncthreads(); \
    float4 q0 = *(const float4*)&swp[par][0][0]; float z0 = swp[par][0][4]; \
    float4 q1 = *(const float4*)&swp[par][1][0]; float z1 = swp[par][1][4]; \
    float4 q2 = *(const float4*)&swp[par][2][0]; float z2 = swp[par][2][4]; \
    float4 q3 = *(const float4*)&swp[par][3][0]; float z3 = swp[par][3][4]; \
    float mm = q0.x; unsigned mi = __float_as_uint(q0.y); \
    float sx = q0.z, sy = q0.w, sz = z0; \
    if (q1.x > mm || (q1.x == mm && __float_as_uint(q1.y) < mi)){ \
      mm = q1.x; mi = __float_as_uint(q1.y); sx = q1.z; sy = q1.w; sz = z1; } \
    if (q2.x > mm || (q2.x == mm && __float_as_uint(q2.y) < mi)){ \
      mm = q2.x; mi = __float_as_uint(q2.y); sx = q2.z; sy = q2.w; sz = z2; } \
    if (q3.x > mm || (q3.x == mm && __float_as_uint(q3.y) < mi)){ \
      mm = q3.x; mi = __float_as_uint(q3.y); sx = q3.z; sy = q3.w; sz = z3; } \
    if (tid == 0) oibuf[s] = (int)mi;

static __device__ __forceinline__ void fps8_body(const float* __restrict__ pts,
    int S, int* __restrict__ oidx, int b, char* smraw)
{
  float (*swp)[4][8] = reinterpret_cast<float(*)[4][8]>(smraw);
  int* oibuf = reinterpret_cast<int*>(smraw + 256);
  int tid = threadIdx.x, wid = tid >> 6;
  const float* P = pts + (size_t)b*2048*3;
  float c0x = P[0], c0y = P[1], c0z = P[2];
  float bm = -1.0f;
  FPS_LOAD(0) FPS_LOAD(1) FPS_LOAD(2) FPS_LOAD(3)
  FPS_LOAD(4) FPS_LOAD(5) FPS_LOAD(6) FPS_LOAD(7)
  if (tid == 0) oibuf[0] = 0;
  for (int s=1; s<S; ++s){
    FPS_REDUCE_AND_PICK
    FPS_MATCH(7) FPS_MATCH(6) FPS_MATCH(5) FPS_MATCH(4)
    FPS_MATCH(3) FPS_MATCH(2) FPS_MATCH(1) FPS_MATCH(0)
    FPS_MIN_AND_MERGE
    if (tid == (int)(idx_w & 255u)){
      float cx = px0, cy = py0, cz = pz0;
      FPS_OWN(1) FPS_OWN(2) FPS_OWN(3) FPS_OWN(4) FPS_OWN(5) FPS_OWN(6) FPS_OWN(7)
      float4* wp = (float4*)&swp[par][wid][0];
      *wp = make_float4(m_w, __uint_as_float(idx_w), cx, cy);
      swp[par][wid][4] = cz;
    }
    FPS_CROSSWAVE
    float nbm = -1.0f;
    FPS_UPD(0) FPS_UPD(1) FPS_UPD(2) FPS_UPD(3)
    FPS_UPD(4) FPS_UPD(5) FPS_UPD(6) FPS_UPD(7)
    bm = nbm;
  }
  __syncthreads();
  for (int s2 = tid; s2 < S; s2 += 256) oidx[b*S + s2] = oibuf[s2];
}

static __device__ __forceinline__ void fps2_body(const float* __restrict__ pts,
    int S, int* __restrict__ oidx, int b, char* smraw)
{
  float (*swp)[4][8] = reinterpret_cast<float(*)[4][8]>(smraw);
  int* oibuf = reinterpret_cast<int*>(smraw + 256);
  int tid = threadIdx.x, wid = tid >> 6;
  const float* P = pts + (size_t)b*512*3;
  float c0x = P[0], c0y = P[1], c0z = P[2];
  float bm = -1.0f;
  FPS_LOAD(0) FPS_LOAD(1)
  if (tid == 0) oibuf[0] = 0;
  for (int s=1; s<S; ++s){
    FPS_REDUCE_AND_PICK
    FPS_MATCH(1) FPS_MATCH(0)
    FPS_MIN_AND_MERGE
    if (tid == (int)(idx_w & 255u)){
      float cx = px0, cy = py0, cz = pz0;
      FPS_OWN(1)
      float4* wp = (float4*)&swp[par][wid][0];
      *wp = make_float4(m_w, __uint_as_float(idx_w), cx, cy);
      swp[par][wid][4] = cz;
    }
    FPS_CROSSWAVE
    float nbm = -1.0f;
    FPS_UPD(0) FPS_UPD(1)
    bm = nbm;
  }
  __syncthreads();
  for (int s2 = tid; s2 < S; s2 += 256) oidx[b*S + s2] = oibuf[s2];
}

// ---------------- per-point GEMV bodies ----------------
template<int C, int O, bool DIFF>
static __device__ __forceinline__ void gemv_body(const float* __restrict__ fin,
    const float* __restrict__ W, float* __restrict__ out, int Npts, int blk)
{
  constexpr int NT = O/8;
  constexpr int LNT = ilog2c(NT);
  int gid = blk*256 + threadIdx.x;
  if (gid >= BB*Npts*NT) return;
  int tile = gid & (NT-1);
  int pn = gid >> LNT;
  const float* frow = fin + (size_t)pn*C;
  float f[C];
  #pragma unroll
  for (int c=0;c<C;c++) f[c] = frow[c];
  float acc[8];
  const float* wbase = W + (tile*8)*(2*C);
  #pragma unroll
  for (int oo=0;oo<8;oo++){
    const float* wrow = wbase + oo*(2*C);
    float a = 0.f;
    #pragma unroll
    for (int c=0;c<C;c++){
      float wv = DIFF ? __fsub_rn(wrow[C+c], wrow[c]) : wrow[c];
      a = __fmaf_rn(wv, f[c], a);
    }
    acc[oo] = a;
  }
  float* orow = out + (size_t)pn*O + tile*8;
  #pragma unroll
  for (int oo=0;oo<8;oo++) orow[oo] = acc[oo];
}

// B-side with gather indirection: row = fin[b*NinB + gidx[pn]]  (DIFF weights)
template<int C, int O, int LNB>
static __device__ __forceinline__ void gemv_bodyBind(const float* __restrict__ fin,
    const float* __restrict__ W, float* __restrict__ out, int blk,
    const int* __restrict__ gidx, int NinB)
{
  constexpr int NT = O/8;
  constexpr int LNT = ilog2c(NT);
  int gid = blk*256 + threadIdx.x;
  if (gid >= BB*(1<<LNB)*NT) return;
  int tile = gid & (NT-1);
  int pn = gid >> LNT;
  int b = pn >> LNB;
  int src = gidx[pn];
  const float* frow = fin + (size_t)(b*NinB + src)*C;
  float f[C];
  #pragma unroll
  for (int c=0;c<C;c++) f[c] = frow[c];
  float acc[8];
  const float* wbase = W + (tile*8)*(2*C);
  #pragma unroll
  for (int oo=0;oo<8;oo++){
    const float* wrow = wbase + oo*(2*C);
    float a = 0.f;
    #pragma unroll
    for (int c=0;c<C;c++){
      float wv = __fsub_rn(wrow[C+c], wrow[c]);
      a = __fmaf_rn(wv, f[c], a);
    }
    acc[oo] = a;
  }
  float* orow = out + (size_t)pn*O + tile*8;
  #pragma unroll
  for (int oo=0;oo<8;oo++) orow[oo] = acc[oo];
}

template<int C, int O, int LNB, bool BIND>
__global__ __launch_bounds__(256) void gemv_dual_kernel(const float* __restrict__ finA,
    const float* __restrict__ finB, const float* __restrict__ W,
    float* __restrict__ outA, float* __restrict__ outB,
    int NptsA, int NptsB, int nAblk, const int* __restrict__ gidxB, int NinB)
{
  int bid = blockIdx.x;
  if (bid < nAblk) gemv_body<C,O,false>(finA, W, outA, NptsA, bid);
  else if constexpr (BIND) gemv_bodyBind<C,O,LNB>(finB, W, outB, bid-nAblk, gidxB, NinB);
  else gemv_body<C,O,true>(finB, W, outB, NptsB, bid-nAblk);
}

// ---------------- GN stats pass v2 body ----------------
template<int O>
static __device__ __forceinline__ void stats2_body(const float* __restrict__ A,
    const float* __restrict__ Bq, const int* __restrict__ idx, int Nq, int Nk,
    double* __restrict__ part, int b, int split, int nsplit, double* sh /*32 dbl*/)
{
  constexpr int O4 = O/4;
  int qlen = Nq / nsplit, q0 = split*qlen;
  int tid = threadIdx.x;
  int pairs = qlen * KNB;
  double s1[4] = {0.0,0.0,0.0,0.0};
  double s2[4] = {0.0,0.0,0.0,0.0};
  for (int p = tid; p < pairs; p += 256){
    int q = q0 + (p >> 4);
    int kk = p & 15;
    int j = idx[(b*Nq+q)*KNB + kk];
    const float* arow = A + (size_t)(b*Nk+j)*O;
    const float* brow = Bq + (size_t)(b*Nq+q)*O;
    #pragma unroll
    for (int g=0; g<4; ++g){
      float cs1 = 0.f, cs2 = 0.f;
      #pragma unroll
      for (int c=0; c<O4; c+=4){
        float4 a4 = *(const float4*)(arow + g*O4 + c);
        float4 b4 = *(const float4*)(brow + g*O4 + c);
        float y0 = a4.x+b4.x, y1 = a4.y+b4.y, y2 = a4.z+b4.z, y3 = a4.w+b4.w;
        cs1 += ((y0+y1)+(y2+y3));
        cs2 = fmaf(y0,y0,cs2); cs2 = fmaf(y1,y1,cs2);
        cs2 = fmaf(y2,y2,cs2); cs2 = fmaf(y3,y3,cs2);
      }
      s1[g] += (double)cs1;
      s2[g] += (double)cs2;
    }
  }
  #pragma unroll
  for (int m=32;m>0;m>>=1){
    #pragma unroll
    for (int g=0; g<4; ++g){
      s1[g] += __shfl_down(s1[g], m);
      s2[g] += __shfl_down(s2[g], m);
    }
  }
  int lane = tid & 63, w = tid >> 6;
  if (lane == 0){
    #pragma unroll
    for (int g=0; g<4; ++g){ sh[w*8+g*2] = s1[g]; sh[w*8+g*2+1] = s2[g]; }
  }
  __syncthreads();
  if (tid == 0){
    #pragma unroll
    for (int g=0; g<4; ++g){
      double t1 = (sh[0*8+g*2]+sh[1*8+g*2]) + (sh[2*8+g*2]+sh[3*8+g*2]);
      double t2 = (sh[0*8+g*2+1]+sh[1*8+g*2+1]) + (sh[2*8+g*2+1]+sh[3*8+g*2+1]);
      int pi = (b*4+g)*nsplit + split;
      part[pi*2] = t1; part[pi*2+1] = t2;
    }
  }
}

template<int O>
__global__ __launch_bounds__(256) void stats2_kernel(const float* __restrict__ A,
    const float* __restrict__ Bq, const int* __restrict__ idx, int Nq, int Nk,
    double* __restrict__ part)
{
  __shared__ double sh[32];
  stats2_body<O>(A, Bq, idx, Nq, Nk, part, blockIdx.x, blockIdx.y, gridDim.y, sh);
}

// ---------------- final pass: inline stats reduce + normalize/lrelu/max ----------
template<int O>
__global__ __launch_bounds__(256) void final_kernel(const float* __restrict__ A,
    const float* __restrict__ Bq, const int* __restrict__ idx,
    const double* __restrict__ part, int nsplit, double cnt,
    const float* __restrict__ gamma, const float* __restrict__ beta,
    float* __restrict__ fout, int Nq, int Nk)
{
  constexpr int LO = ilog2c(O);
  constexpr int LO4 = ilog2c(O/4);
  __shared__ float smu[4], srs[4];
  int b = blockIdx.y;
  if (threadIdx.x < 4){
    int g = threadIdx.x;
    int t0 = b*4+g;
    double s1=0.0, s2=0.0;
    for (int i=0;i<nsplit;i++){ s1 += part[(t0*nsplit+i)*2]; s2 += part[(t0*nsplit+i)*2+1]; }
    double mean = s1/cnt;
    double var = s2/cnt - mean*mean;
    double rstd = 1.0 / sqrt(var + 1e-5);
    smu[g] = (float)mean;
    srs[g] = (float)rstd;
  }
  __syncthreads();
  int t = blockIdx.x*256 + threadIdx.x;
  if (t >= Nq*O) return;
  int o = t & (O-1);
  int q = t >> LO;
  int g = o >> LO4;
  float mu   = smu[g];
  float rstd = srs[g];
  float gam = gamma[o], bet = beta[o];
  float bq = Bq[(b*Nq+q)*O + o];
  const int* ip = idx + (b*Nq+q)*KNB;
  float m = -__builtin_inff();
  #pragma unroll
  for (int kk=0;kk<KNB;kk++){
    int j = ip[kk];
    float y = A[(b*Nk+j)*O + o] + bq;
    float yn = __fmul_rn(__fsub_rn(y, mu), rstd);
    float yv = __fadd_rn(__fmul_rn(yn, gam), bet);
    float l = yv >= 0.f ? yv : 0.2f*yv;
    m = fmaxf(m, l);
  }
  fout[(b*Nq+q)*O + o] = m;
}

// ---------------- gathers ----------------
static __device__ __forceinline__ void gatherc_body(const int* __restrict__ fidx,
    const float* __restrict__ pts, float* __restrict__ cq, int Nin, int Nout, int blk)
{
  int gid = blk*256 + threadIdx.x;
  if (gid >= BB*Nout) return;
  int b = gid / Nout;
  int i = gid - b*Nout;
  int src = fidx[b*Nout + i];
  #pragma unroll
  for (int c=0;c<3;c++) cq[gid*3+c] = pts[(b*Nin+src)*3+c];
}

__global__ __launch_bounds__(256) void gatherc_kernel(const int* __restrict__ fidx,
    const float* __restrict__ pts, float* __restrict__ cq, int Nin, int Nout)
{
  gatherc_body(fidx, pts, cq, Nin, Nout, blockIdx.x);
}

// ---------------- fused1: fps0 (32) | knn1-512chunk (1024) | proj (256) ------------
__global__ __launch_bounds__(256) void fused1_kernel(const float* __restrict__ x,
    const float* __restrict__ w_in, const float* __restrict__ b_in,
    float* __restrict__ f0, float* __restrict__ pd1, unsigned short* __restrict__ pi1,
    int* __restrict__ fidx0)
{
  __shared__ __align__(16) char sm[4096];
  int bid = blockIdx.x;
  if (bid < 32){
    __builtin_amdgcn_s_setprio(3);
    fps8_body(x, 512, fidx0, bid, sm);
  } else if (bid < 32+1024){
    int r = bid - 32;
    int b = r & 31; int rest = r >> 5;      // rest in [0,32): qcb = rest&7, kc = rest>>3
    knn_part512_body(x, x, 2048, 2048, 4, pd1, pi1, b, rest & 7, rest >> 3, (float4*)sm);
  } else {
    proj_body(x, w_in, b_in, f0, bid - 1056);
  }
}

// ---------------- fused2: fps1(32) | knn2(512) | knn3(128) | merge1(256) | gemv1(2048)
__global__ __launch_bounds__(256) void fused2_kernel(const float* __restrict__ coorq1,
    const float* __restrict__ x,
    float* __restrict__ pd2, unsigned char* __restrict__ pi2,
    float* __restrict__ pd3, unsigned char* __restrict__ pi3,
    int* __restrict__ fidx1,
    const float* __restrict__ pd1, const unsigned short* __restrict__ pi1,
    int* __restrict__ idx1,
    const float* __restrict__ f0, const float* __restrict__ w1,
    float* __restrict__ A1, float* __restrict__ B1)
{
  __shared__ __align__(16) char sm[4096];
  int bid = blockIdx.x;
  if (bid < 32){
    __builtin_amdgcn_s_setprio(3);
    fps2_body(coorq1, 128, fidx1, bid, sm);
  } else if (bid < 32+512){
    int r = bid - 32;
    int b = r & 31; int rest = r >> 5;
    knn_part_body(coorq1, x, 512, 2048, 8, pd2, pi2, b, rest & 1, rest >> 1,
                  (float4*)sm, nullptr, 0);
  } else if (bid < 32+512+128){
    int r = bid - 544;
    int b = r & 31; int rest = r >> 5;
    knn_part_body(coorq1, coorq1, 512, 512, 2, pd3, pi3, b, rest & 1, rest >> 1,
                  (float4*)sm, nullptr, 0);
  } else if (bid < 928){
    knn_merge512_body(pd1, pi1, 2048, 4, idx1, bid - 672);
  } else if (bid < 1952){
    gemv_body<8,32,false>(f0, w1, A1, 2048, bid - 928);
  } else {
    gemv_body<8,32,true>(f0, w1, B1, 2048, bid - 1952);
  }
}

// ---------------- fused3: stats1(256) | merge2(64) | merge3(64) | knn4-ind(64) | gatherc4(16)
__global__ __launch_bounds__(256) void fused3_kernel(
    const float* __restrict__ A1, const float* __restrict__ B1,
    const int* __restrict__ idx1, double* __restrict__ part,
    const float* __restrict__ pd2, const unsigned char* __restrict__ pi2, int* __restrict__ idx2,
    const float* __restrict__ pd3, const unsigned char* __restrict__ pi3, int* __restrict__ idx3,
    const float* __restrict__ coorq1, const int* __restrict__ fidx1,
    float* __restrict__ pd4, unsigned char* __restrict__ pi4,
    float* __restrict__ coor_out)
{
  __shared__ __align__(16) char sm[4096];
  int bid = blockIdx.x;
  if (bid < 256){
    stats2_body<32>(A1, B1, idx1, 2048, 2048, part, bid >> 3, bid & 7, 8, (double*)sm);
  } else if (bid < 320){
    knn_merge_body(pd2, pi2, 512, 8, idx2, bid - 256);
  } else if (bid < 384){
    knn_merge_body(pd3, pi3, 512, 2, idx3, bid - 320);
  } else if (bid < 448){
    int r = bid - 384;
    int b = r & 31; int kc = r >> 5;
    knn_part_body(coorq1, coorq1, 128, 512, 2, pd4, pi4, b, 0, kc,
                  (float4*)sm, fidx1, 512);
  } else {
    gatherc_body(fidx1, coorq1, coor_out, 512, 128, bid - 448);
  }
}

// ---------------- fused4: gemv2 A(2048) + B-ind(512) | merge4(16) --------------------
__global__ __launch_bounds__(256) void fused4_kernel(const float* __restrict__ f1,
    const float* __restrict__ w2, float* __restrict__ A, float* __restrict__ Bq,
    const int* __restrict__ fidx0,
    const float* __restrict__ pd4, const unsigned char* __restrict__ pi4,
    int* __restrict__ idx4)
{
  int bid = blockIdx.x;
  if (bid < 2048) gemv_body<32,64,false>(f1, w2, A, 2048, bid);
  else if (bid < 2560) gemv_bodyBind<32,64,9>(f1, w2, Bq, bid - 2048, fidx0, 2048);
  else knn_merge_body(pd4, pi4, 128, 2, idx4, bid - 2560);
}

extern "C" void kernel_launch(void* const* d_in, const int* in_sizes, int n_in,
                              void* d_out, int out_size, void* d_ws, size_t ws_size,
                              hipStream_t stream)
{
  (void)in_sizes; (void)n_in; (void)out_size; (void)ws_size;
  const float* x    = (const float*)d_in[0];
  const float* w_in = (const float*)d_in[1];
  const float* b_in = (const float*)d_in[2];
  const float* w1 = (const float*)d_in[3];
  const float* g1 = (const float*)d_in[4];
  const float* be1= (const float*)d_in[5];
  const float* w2 = (const float*)d_in[6];
  const float* g2 = (const float*)d_in[7];
  const float* be2= (const float*)d_in[8];
  const float* w3 = (const float*)d_in[9];
  const float* g3 = (const float*)d_in[10];
  const float* be3= (const float*)d_in[11];
  const float* w4 = (const float*)d_in[12];
  const float* g4 = (const float*)d_in[13];
  const float* be4= (const float*)d_in[14];

  float* out = (float*)d_out;
  float* coor_out = out;                    // (32,128,3)
  float* f_out = out + BB*128*3;            // (32,128,256)

  char* ws = (char*)d_ws;
  size_t off = 0;
  auto alloc = [&](size_t bytes)->void*{ void* p = ws + off; off += (bytes + 255) & ~(size_t)255; return p; };

  // ---- persistent buffers (~37 MB) ----
  float* f0     = (float*)alloc((size_t)BB*2048*8*4);
  int*   idx1   = (int*)  alloc((size_t)BB*2048*16*4);
  float* f1     = (float*)alloc((size_t)BB*2048*32*4);
  double* part  = (double*)alloc((size_t)BB*4*8*2*8);
  int*   fidx0  = (int*)  alloc((size_t)BB*512*4);
  float* coorq1 = (float*)alloc((size_t)BB*512*3*4);
  int*   idx2   = (int*)  alloc((size_t)BB*512*16*4);
  float* f2     = (float*)alloc((size_t)BB*512*64*4);
  int*   idx3   = (int*)  alloc((size_t)BB*512*16*4);
  float* f3     = (float*)alloc((size_t)BB*512*64*4);
  int*   fidx1  = (int*)  alloc((size_t)BB*128*4);
  int*   idx4   = (int*)  alloc((size_t)BB*128*16*4);
  float* pd2          = (float*)alloc((size_t)BB*512*8*KNB*4);
  unsigned char* pi2  = (unsigned char*)alloc((size_t)BB*512*8*KNB);
  float* pd3          = (float*)alloc((size_t)BB*512*2*KNB*4);
  unsigned char* pi3  = (unsigned char*)alloc((size_t)BB*512*2*KNB);
  float* pd4          = (float*)alloc((size_t)BB*128*2*KNB*4);
  unsigned char* pi4  = (unsigned char*)alloc((size_t)BB*128*2*KNB);

  // ---- union region U (40 MB) ----
  // fused2 uses: pd1[0,16M) + pi1[16M,24M) + A1[24M,32M) + B1[32M,40M) - all disjoint.
  // stage2+ (after fused3/final1): A[0,16M), Bq[20M,24M) - pd1/pi1 dead by then;
  // A1/B1 dead after final1 which precedes fused4 (first stage2+ writer).
  char* U = (char*)alloc((size_t)40<<20);
  float* pd1          = (float*)U;
  unsigned short* pi1 = (unsigned short*)(U + ((size_t)16<<20));
  float* A1 = (float*)(U + ((size_t)24<<20));
  float* B1 = (float*)(U + ((size_t)32<<20));
  float* A  = (float*)U;
  float* Bq = (float*)(U + ((size_t)20<<20));

  auto cdiv = [](int a, int b){ return (a+b-1)/b; };

  // 1. fps0 | knn1 | proj
  fused1_kernel<<<1312,256,0,stream>>>(x, w_in, b_in, f0, pd1, pi1, fidx0);
  // 2. query coords for stages 2/3
  gatherc_kernel<<<cdiv(BB*512,256),256,0,stream>>>(fidx0, x, coorq1, 2048, 512);
  // 3. fps1 | knn2 | knn3 | merge1 | gemv1  (all hidden under fps1 chain)
  fused2_kernel<<<2976,256,0,stream>>>(coorq1, x, pd2, pi2, pd3, pi3, fidx1,
                                       pd1, pi1, idx1, f0, w1, A1, B1);
  // 4. stats1 | merge2 | merge3 | knn4-indirect | gatherc4
  fused3_kernel<<<464,256,0,stream>>>(A1, B1, idx1, part, pd2, pi2, idx2,
                                      pd3, pi3, idx3, coorq1, fidx1, pd4, pi4, coor_out);
  // 5. final1 -> f1
  final_kernel<32><<<dim3(cdiv(2048*32,256),BB),256,0,stream>>>(A1, B1, idx1, part, 8,
      8.0*2048*16, g1, be1, f1, 2048, 2048);
  // 6. gemv2 (A + B-indirect) | merge4
  fused4_kernel<<<2576,256,0,stream>>>(f1, w2, A, Bq, fidx0, pd4, pi4, idx4);
  // 7-8. stage 2 stats/final
  stats2_kernel<64><<<dim3(BB,8),256,0,stream>>>(A, Bq, idx2, 512, 2048, part);
  final_kernel<64><<<dim3(cdiv(512*64,256),BB),256,0,stream>>>(A, Bq, idx2, part, 8,
      16.0*512*16, g2, be2, f2, 512, 2048);
  // 9-11. stage 3
  gemv_dual_kernel<64,64,0,false><<<1024,256,0,stream>>>(f2, f2, w3, A, Bq,
      512, 512, 512, nullptr, 0);
  stats2_kernel<64><<<dim3(BB,8),256,0,stream>>>(A, Bq, idx3, 512, 512, part);
  final_kernel<64><<<dim3(cdiv(512*64,256),BB),256,0,stream>>>(A, Bq, idx3, part, 8,
      16.0*512*16, g3, be3, f3, 512, 512);
  // 12-14. stage 4 (B-indirect via fidx1)
  gemv_dual_kernel<64,256,7,true><<<2560,256,0,stream>>>(f3, f3, w4, A, Bq,
      512, 128, 2048, fidx1, 512);
  stats2_kernel<256><<<dim3(BB,8),256,0,stream>>>(A, Bq, idx4, 128, 512, part);
  final_kernel<256><<<dim3(cdiv(128*256,256),BB),256,0,stream>>>(A, Bq, idx4, part, 8,
      64.0*128*16, g4, be4, f_out, 128, 512);
}

// Round 17
// 1195.586 us; speedup vs baseline: 1.5022x; 1.0189x over previous
//
#include <hip/hip_runtime.h>

#define BB 32
#define NPTS0 2048
#define KNB 16
#define KC 256

constexpr int ilog2c(int n){ int l=0; while(n>1){ n>>=1; ++l; } return l; }

static __device__ __forceinline__ float sq3(float a, float b, float c){
  return __fadd_rn(__fadd_rn(__fmul_rn(a,a),__fmul_rn(b,b)),__fmul_rn(c,c));
}

template<int CTRL, int RM>
static __device__ __forceinline__ float dpp_maxf(float v){
  int s = __builtin_amdgcn_update_dpp(__float_as_int(v), __float_as_int(v), CTRL, RM, 0xF, false);
  return fmaxf(v, __int_as_float(s));
}
template<int CTRL, int RM>
static __device__ __forceinline__ unsigned dpp_minu(unsigned v){
  unsigned s = (unsigned)__builtin_amdgcn_update_dpp((int)v, (int)v, CTRL, RM, 0xF, false);
  return s < v ? s : v;
}

// ---------------- proj body ----------------
static __device__ __forceinline__ void proj_body(const float* __restrict__ x,
    const float* __restrict__ w, const float* __restrict__ bias, float* __restrict__ f0,
    int blk)
{
  int gid = blk*256 + threadIdx.x;
  if (gid >= BB*NPTS0) return;
  float x0 = x[gid*3+0], x1 = x[gid*3+1], x2 = x[gid*3+2];
  #pragma unroll
  for (int o = 0; o < 8; ++o){
    float acc = __fmul_rn(w[o*3+0], x0);
    acc = __fmaf_rn(w[o*3+1], x1, acc);
    acc = __fmaf_rn(w[o*3+2], x2, acc);
    f0[gid*8+o] = __fadd_rn(acc, bias[o]);
  }
}

// ---------------- NAMED-SCALAR top-16 machinery ----------------
#define KDECL(I) float th##I = __builtin_inff(); int ti##I = 0;
#define KINS(I,J) if (th##I < th##J){ float tv=th##I; th##I=th##J; th##J=tv; \
                                      int tj=ti##I; ti##I=ti##J; ti##J=tj; }
#define KCASCADE KINS(15,14) KINS(14,13) KINS(13,12) KINS(12,11) KINS(11,10) \
  KINS(10,9) KINS(9,8) KINS(8,7) KINS(7,6) KINS(6,5) KINS(5,4) KINS(4,3) \
  KINS(3,2) KINS(2,1) KINS(1,0)
#define KALLDECL KDECL(0) KDECL(1) KDECL(2) KDECL(3) KDECL(4) KDECL(5) KDECL(6) KDECL(7) \
  KDECL(8) KDECL(9) KDECL(10) KDECL(11) KDECL(12) KDECL(13) KDECL(14) KDECL(15)
#define KST(I) pd[base+I] = th##I; pi[base+I] = (unsigned char)ti##I;
#define KST16(I) pd[base+I] = th##I; pi[base+I] = (unsigned short)ti##I;
#define MST(I) oidx[obase+I] = ti##I;

// stage-1 kNN: 512-key chunks, two sequential 256-key LDS tiles, u16 local idx.
static __device__ __forceinline__ void knn_part512_body(const float* __restrict__ qpts,
    const float* __restrict__ kpts, int Nq, int Nk, int nkc,
    float* __restrict__ pd, unsigned short* __restrict__ pi,
    int b, int qcb, int kc, float4* kk4)
{
  int tid = threadIdx.x;
  int q = qcb*256 + tid;
  float qx = qpts[(b*Nq+q)*3+0], qy = qpts[(b*Nq+q)*3+1], qz = qpts[(b*Nq+q)*3+2];
  float qq = sq3(qx,qy,qz);
  KALLDECL
  #pragma unroll
  for (int half=0; half<2; ++half){
    __syncthreads();
    {
      int j = kc*512 + half*256 + tid;
      float a = kpts[(b*Nk+j)*3+0];
      float c = kpts[(b*Nk+j)*3+1];
      float dd = kpts[(b*Nk+j)*3+2];
      kk4[tid] = make_float4(a, c, dd, sq3(a,c,dd));
    }
    __syncthreads();
    for (int j=0;j<KC;j++){
      float4 k4 = kk4[j];
      float dot = __fmul_rn(qx,k4.x);
      dot = __fmaf_rn(qy,k4.y,dot);
      dot = __fmaf_rn(qz,k4.z,dot);
      float d = __fadd_rn(__fsub_rn(qq, __fmul_rn(2.0f,dot)), k4.w);
      if (d < th15){
        th15 = d; ti15 = half*256 + j;
        KCASCADE
      }
    }
  }
  size_t base = ((size_t)(b*Nq+q)*nkc + kc)*KNB;
  KST16(0) KST16(1) KST16(2) KST16(3) KST16(4) KST16(5) KST16(6) KST16(7)
  KST16(8) KST16(9) KST16(10) KST16(11) KST16(12) KST16(13) KST16(14) KST16(15)
}

// generic 256-key-chunk kNN, optional indirect queries
static __device__ __forceinline__ void knn_part_body(const float* __restrict__ qpts,
    const float* __restrict__ kpts, int Nq, int Nk, int nkc,
    float* __restrict__ pd, unsigned char* __restrict__ pi,
    int b, int qcb, int kc, float4* kk4, const int* __restrict__ qidx, int NinQ)
{
  int tid = threadIdx.x;
  {
    int j = kc*KC + tid;
    float a = kpts[(b*Nk+j)*3+0];
    float c = kpts[(b*Nk+j)*3+1];
    float d = kpts[(b*Nk+j)*3+2];
    kk4[tid] = make_float4(a, c, d, sq3(a,c,d));
  }
  __syncthreads();
  int q = qcb*256 + tid;
  if (q >= Nq) return;
  int qrow = qidx ? (b*NinQ + qidx[b*Nq+q]) : (b*Nq+q);
  float qx = qpts[qrow*3+0], qy = qpts[qrow*3+1], qz = qpts[qrow*3+2];
  float qq = sq3(qx,qy,qz);
  KALLDECL
  for (int j=0;j<KC;j++){
    float4 k4 = kk4[j];
    float dot = __fmul_rn(qx,k4.x);
    dot = __fmaf_rn(qy,k4.y,dot);
    dot = __fmaf_rn(qz,k4.z,dot);
    float d = __fadd_rn(__fsub_rn(qq, __fmul_rn(2.0f,dot)), k4.w);
    if (d < th15){
      th15 = d; ti15 = j;
      KCASCADE
    }
  }
  size_t base = ((size_t)(b*Nq+q)*nkc + kc)*KNB;
  KST(0) KST(1) KST(2) KST(3) KST(4) KST(5) KST(6) KST(7)
  KST(8) KST(9) KST(10) KST(11) KST(12) KST(13) KST(14) KST(15)
}

static __device__ __forceinline__ void knn_merge_body(const float* __restrict__ pd,
    const unsigned char* __restrict__ pi, int Nq, int nkc, int* __restrict__ oidx,
    int blk)
{
  int gid = blk*256 + threadIdx.x;
  if (gid >= BB*Nq) return;
  KALLDECL
  size_t base = (size_t)gid*nkc*KNB;
  for (int kc=0;kc<nkc;kc++){
    size_t cb = base + (size_t)kc*KNB;
    for (int i=0;i<KNB;i++){
      float d = pd[cb+i];
      if (d >= th15) break;
      int j = kc*KC + (int)pi[cb+i];
      th15 = d; ti15 = j;
      KCASCADE
    }
  }
  int obase = gid*KNB;
  MST(0) MST(1) MST(2) MST(3) MST(4) MST(5) MST(6) MST(7)
  MST(8) MST(9) MST(10) MST(11) MST(12) MST(13) MST(14) MST(15)
}

static __device__ __forceinline__ void knn_merge512_body(const float* __restrict__ pd,
    const unsigned short* __restrict__ pi, int Nq, int nkc, int* __restrict__ oidx,
    int blk)
{
  int gid = blk*256 + threadIdx.x;
  if (gid >= BB*Nq) return;
  KALLDECL
  size_t base = (size_t)gid*nkc*KNB;
  for (int kc=0;kc<nkc;kc++){
    size_t cb = base + (size_t)kc*KNB;
    for (int i=0;i<KNB;i++){
      float d = pd[cb+i];
      if (d >= th15) break;
      int j = kc*512 + (int)pi[cb+i];
      th15 = d; ti15 = j;
      KCASCADE
    }
  }
  int obase = gid*KNB;
  MST(0) MST(1) MST(2) MST(3) MST(4) MST(5) MST(6) MST(7)
  MST(8) MST(9) MST(10) MST(11) MST(12) MST(13) MST(14) MST(15)
}

// ---------------- FPS bodies: 4-wave + LDS-buffered output -------------------------
#define FPS_LOAD(T) float px##T, py##T, pz##T, d##T; { int i_=T*256+tid; \
  px##T=P[i_*3+0]; py##T=P[i_*3+1]; pz##T=P[i_*3+2]; \
  float dx_=__fsub_rn(px##T,c0x), dy_=__fsub_rn(py##T,c0y), dz_=__fsub_rn(pz##T,c0z); \
  d##T=sq3(dx_,dy_,dz_); bm=fmaxf(bm,d##T); }
#define FPS_MATCH(T) if (d##T == m_w) ci = (unsigned)(T*256 + tid);
#define FPS_OWN(T) if ((idx_w>>8) == T##u){ cx=px##T; cy=py##T; cz=pz##T; }
#define FPS_UPD(T) { float dx_=__fsub_rn(px##T,sx), dy_=__fsub_rn(py##T,sy), dz_=__fsub_rn(pz##T,sz); \
  float nd_=sq3(dx_,dy_,dz_); d##T=fminf(d##T,nd_); nbm=fmaxf(nbm,d##T); }

#define FPS_REDUCE_AND_PICK \
    float v = bm; \
    v = dpp_maxf<0x111, 0xF>(v); \
    v = dpp_maxf<0x112, 0xF>(v); \
    v = dpp_maxf<0x114, 0xF>(v); \
    v = dpp_maxf<0x118, 0xF>(v); \
    v = dpp_maxf<0x142, 0xA>(v); \
    v = dpp_maxf<0x143, 0xC>(v); \
    float m_w = __int_as_float(__builtin_amdgcn_readlane(__float_as_int(v), 63)); \
    unsigned ci = 0xFFFFFFFFu;

#define FPS_MIN_AND_MERGE \
    ci = dpp_minu<0x111, 0xF>(ci); \
    ci = dpp_minu<0x112, 0xF>(ci); \
    ci = dpp_minu<0x114, 0xF>(ci); \
    ci = dpp_minu<0x118, 0xF>(ci); \
    ci = dpp_minu<0x142, 0xA>(ci); \
    ci = dpp_minu<0x143, 0xC>(ci); \
    unsigned idx_w = (unsigned)__builtin_amdgcn_readlane((int)ci, 63); \
    int par = s & 1;

#define FPS_CROSSWAVE \
    __syncthreads(); \
    float4 q0 = *(const float4*)&swp[par][0][0]; float z0 = swp[par][0][4]; \
    float4 q1 = *(const float4*)&swp[par][1][0]; float z1 = swp[par][1][4]; \
    float4 q2 = *(const float4*)&swp[par][2][0]; float z2 = swp[par][2][4]; \
    float4 q3 = *(const float4*)&swp[par][3][0]; float z3 = swp[par][3][4]; \
    float mm = q0.x; unsigned mi = __float_as_uint(q0.y); \
    float sx = q0.z, sy = q0.w, sz = z0; \
    if (q1.x > mm || (q1.x == mm && __float_as_uint(q1.y) < mi)){ \
      mm = q1.x; mi = __float_as_uint(q1.y); sx = q1.z; sy = q1.w; sz = z1; } \
    if (q2.x > mm || (q2.x == mm && __float_as_uint(q2.y) < mi)){ \
      mm = q2.x; mi = __float_as_uint(q2.y); sx = q2.z; sy = q2.w; sz = z2; } \
    if (q3.x > mm || (q3.x == mm && __float_as_uint(q3.y) < mi)){ \
      mm = q3.x; mi = __float_as_uint(q3.y); sx = q3.z; sy = q3.w; sz = z3; } \
    if (tid == 0) oibuf[s] = (int)mi;

static __device__ __forceinline__ void fps8_body(const float* __restrict__ pts,
    int S, int* __restrict__ oidx, int b, char* smraw)
{
  float (*swp)[4][8] = reinterpret_cast<float(*)[4][8]>(smraw);
  int* oibuf = reinterpret_cast<int*>(smraw + 256);
  int tid = threadIdx.x, wid = tid >> 6;
  const float* P = pts + (size_t)b*2048*3;
  float c0x = P[0], c0y = P[1], c0z = P[2];
  float bm = -1.0f;
  FPS_LOAD(0) FPS_LOAD(1) FPS_LOAD(2) FPS_LOAD(3)
  FPS_LOAD(4) FPS_LOAD(5) FPS_LOAD(6) FPS_LOAD(7)
  if (tid == 0) oibuf[0] = 0;
  for (int s=1; s<S; ++s){
    FPS_REDUCE_AND_PICK
    FPS_MATCH(7) FPS_MATCH(6) FPS_MATCH(5) FPS_MATCH(4)
    FPS_MATCH(3) FPS_MATCH(2) FPS_MATCH(1) FPS_MATCH(0)
    FPS_MIN_AND_MERGE
    if (tid == (int)(idx_w & 255u)){
      float cx = px0, cy = py0, cz = pz0;
      FPS_OWN(1) FPS_OWN(2) FPS_OWN(3) FPS_OWN(4) FPS_OWN(5) FPS_OWN(6) FPS_OWN(7)
      float4* wp = (float4*)&swp[par][wid][0];
      *wp = make_float4(m_w, __uint_as_float(idx_w), cx, cy);
      swp[par][wid][4] = cz;
    }
    FPS_CROSSWAVE
    float nbm = -1.0f;
    FPS_UPD(0) FPS_UPD(1) FPS_UPD(2) FPS_UPD(3)
    FPS_UPD(4) FPS_UPD(5) FPS_UPD(6) FPS_UPD(7)
    bm = nbm;
  }
  __syncthreads();
  for (int s2 = tid; s2 < S; s2 += 256) oidx[b*S + s2] = oibuf[s2];
}

static __device__ __forceinline__ void fps2_body(const float* __restrict__ pts,
    int S, int* __restrict__ oidx, int b, char* smraw)
{
  float (*swp)[4][8] = reinterpret_cast<float(*)[4][8]>(smraw);
  int* oibuf = reinterpret_cast<int*>(smraw + 256);
  int tid = threadIdx.x, wid = tid >> 6;
  const float* P = pts + (size_t)b*512*3;
  float c0x = P[0], c0y = P[1], c0z = P[2];
  float bm = -1.0f;
  FPS_LOAD(0) FPS_LOAD(1)
  if (tid == 0) oibuf[0] = 0;
  for (int s=1; s<S; ++s){
    FPS_REDUCE_AND_PICK
    FPS_MATCH(1) FPS_MATCH(0)
    FPS_MIN_AND_MERGE
    if (tid == (int)(idx_w & 255u)){
      float cx = px0, cy = py0, cz = pz0;
      FPS_OWN(1)
      float4* wp = (float4*)&swp[par][wid][0];
      *wp = make_float4(m_w, __uint_as_float(idx_w), cx, cy);
      swp[par][wid][4] = cz;
    }
    FPS_CROSSWAVE
    float nbm = -1.0f;
    FPS_UPD(0) FPS_UPD(1)
    bm = nbm;
  }
  __syncthreads();
  for (int s2 = tid; s2 < S; s2 += 256) oidx[b*S + s2] = oibuf[s2];
}

// ---------------- per-point GEMV bodies ----------------
template<int C, int O, bool DIFF>
static __device__ __forceinline__ void gemv_body(const float* __restrict__ fin,
    const float* __restrict__ W, float* __restrict__ out, int Npts, int blk)
{
  constexpr int NT = O/8;
  constexpr int LNT = ilog2c(NT);
  int gid = blk*256 + threadIdx.x;
  if (gid >= BB*Npts*NT) return;
  int tile = gid & (NT-1);
  int pn = gid >> LNT;
  const float* frow = fin + (size_t)pn*C;
  float f[C];
  #pragma unroll
  for (int c=0;c<C;c++) f[c] = frow[c];
  float acc[8];
  const float* wbase = W + (tile*8)*(2*C);
  #pragma unroll
  for (int oo=0;oo<8;oo++){
    const float* wrow = wbase + oo*(2*C);
    float a = 0.f;
    #pragma unroll
    for (int c=0;c<C;c++){
      float wv = DIFF ? __fsub_rn(wrow[C+c], wrow[c]) : wrow[c];
      a = __fmaf_rn(wv, f[c], a);
    }
    acc[oo] = a;
  }
  float* orow = out + (size_t)pn*O + tile*8;
  #pragma unroll
  for (int oo=0;oo<8;oo++) orow[oo] = acc[oo];
}

template<int C, int O, int LNB>
static __device__ __forceinline__ void gemv_bodyBind(const float* __restrict__ fin,
    const float* __restrict__ W, float* __restrict__ out, int blk,
    const int* __restrict__ gidx, int NinB)
{
  constexpr int NT = O/8;
  constexpr int LNT = ilog2c(NT);
  int gid = blk*256 + threadIdx.x;
  if (gid >= BB*(1<<LNB)*NT) return;
  int tile = gid & (NT-1);
  int pn = gid >> LNT;
  int b = pn >> LNB;
  int src = gidx[pn];
  const float* frow = fin + (size_t)(b*NinB + src)*C;
  float f[C];
  #pragma unroll
  for (int c=0;c<C;c++) f[c] = frow[c];
  float acc[8];
  const float* wbase = W + (tile*8)*(2*C);
  #pragma unroll
  for (int oo=0;oo<8;oo++){
    const float* wrow = wbase + oo*(2*C);
    float a = 0.f;
    #pragma unroll
    for (int c=0;c<C;c++){
      float wv = __fsub_rn(wrow[C+c], wrow[c]);
      a = __fmaf_rn(wv, f[c], a);
    }
    acc[oo] = a;
  }
  float* orow = out + (size_t)pn*O + tile*8;
  #pragma unroll
  for (int oo=0;oo<8;oo++) orow[oo] = acc[oo];
}

template<int C, int O, int LNB, bool BIND>
__global__ __launch_bounds__(256) void gemv_dual_kernel(const float* __restrict__ finA,
    const float* __restrict__ finB, const float* __restrict__ W,
    float* __restrict__ outA, float* __restrict__ outB,
    int NptsA, int NptsB, int nAblk, const int* __restrict__ gidxB, int NinB)
{
  int bid = blockIdx.x;
  if (bid < nAblk) gemv_body<C,O,false>(finA, W, outA, NptsA, bid);
  else if constexpr (BIND) gemv_bodyBind<C,O,LNB>(finB, W, outB, bid-nAblk, gidxB, NinB);
  else gemv_body<C,O,true>(finB, W, outB, NptsB, bid-nAblk);
}

// ---------------- stats + neighbor-max/min in ONE gather pass ----------------
// Thread per (q, 4-channel chunk). ymax/ymin are thread-local (no cross-lane).
// Per-group sums via deterministic shfl_xor span-reduce (fixed mask order).
template<int O>
static __device__ __forceinline__ void statsmm_body(const float* __restrict__ A,
    const float* __restrict__ Bq, const int* __restrict__ idx, int Nq, int Nk,
    double* __restrict__ part, float* __restrict__ ymax, float* __restrict__ ymin,
    int b, int split, int nsplit, double* sh /*32 dbl*/)
{
  constexpr int NCH = O/4;              // 4-channel chunks per row
  constexpr int LNCH = ilog2c(NCH);
  constexpr int W = NCH/4;              // chunks per group
  int qlen = Nq / nsplit, q0 = split*qlen;
  int tid = threadIdx.x;
  int items = qlen * NCH;               // multiple of 256 for all stages
  double s1 = 0.0, s2 = 0.0;
  for (int p = tid; p < items; p += 256){
    int q = q0 + (p >> LNCH);
    int ch = p & (NCH-1);               // constant per thread (256 % NCH == 0)
    const int* ip = idx + (b*Nq+q)*KNB;
    size_t yo = (size_t)(b*Nq+q)*O + ch*4;
    float4 b4 = *(const float4*)(Bq + yo);
    float mx0=-__builtin_inff(), mx1=mx0, mx2=mx0, mx3=mx0;
    float mn0= __builtin_inff(), mn1=mn0, mn2=mn0, mn3=mn0;
    float cs1 = 0.f, cs2 = 0.f;
    #pragma unroll
    for (int kk=0; kk<KNB; ++kk){
      int j = ip[kk];
      float4 a4 = *(const float4*)(A + (size_t)(b*Nk+j)*O + ch*4);
      float y0 = a4.x+b4.x, y1 = a4.y+b4.y, y2 = a4.z+b4.z, y3 = a4.w+b4.w;
      cs1 += ((y0+y1)+(y2+y3));
      cs2 = fmaf(y0,y0,cs2); cs2 = fmaf(y1,y1,cs2);
      cs2 = fmaf(y2,y2,cs2); cs2 = fmaf(y3,y3,cs2);
      mx0=fmaxf(mx0,y0); mx1=fmaxf(mx1,y1); mx2=fmaxf(mx2,y2); mx3=fmaxf(mx3,y3);
      mn0=fminf(mn0,y0); mn1=fminf(mn1,y1); mn2=fminf(mn2,y2); mn3=fminf(mn3,y3);
    }
    *(float4*)(ymax + yo) = make_float4(mx0,mx1,mx2,mx3);
    *(float4*)(ymin + yo) = make_float4(mn0,mn1,mn2,mn3);
    s1 += (double)cs1;
    s2 += (double)cs2;
  }
  // deterministic span-reduce: within-group chunk bits + cross-q bits
  if constexpr (W >= 2){ s1 += __shfl_xor(s1,1);  s2 += __shfl_xor(s2,1);  }
  if constexpr (W >= 4){ s1 += __shfl_xor(s1,2);  s2 += __shfl_xor(s2,2);  }
  if constexpr (W >= 8){ s1 += __shfl_xor(s1,4);  s2 += __shfl_xor(s2,4);  }
  if constexpr (W >= 16){ s1 += __shfl_xor(s1,8); s2 += __shfl_xor(s2,8);  }
  if constexpr (NCH <= 8){  s1 += __shfl_xor(s1,8);  s2 += __shfl_xor(s2,8);  }
  if constexpr (NCH <= 16){ s1 += __shfl_xor(s1,16); s2 += __shfl_xor(s2,16); }
  if constexpr (NCH <= 32){ s1 += __shfl_xor(s1,32); s2 += __shfl_xor(s2,32); }
  int lane = tid & 63, wv = tid >> 6;
  if (lane < NCH && (lane & (W-1)) == 0){
    int g = lane / W;
    sh[wv*8+g*2] = s1; sh[wv*8+g*2+1] = s2;
  }
  __syncthreads();
  if (tid == 0){
    #pragma unroll
    for (int g=0; g<4; ++g){
      double t1 = (sh[0*8+g*2]+sh[1*8+g*2]) + (sh[2*8+g*2]+sh[3*8+g*2]);
      double t2 = (sh[0*8+g*2+1]+sh[1*8+g*2+1]) + (sh[2*8+g*2+1]+sh[3*8+g*2+1]);
      int pi = (b*4+g)*nsplit + split;
      part[pi*2] = t1; part[pi*2+1] = t2;
    }
  }
}

template<int O>
__global__ __launch_bounds__(256) void statsmm_kernel(const float* __restrict__ A,
    const float* __restrict__ Bq, const int* __restrict__ idx, int Nq, int Nk,
    double* __restrict__ part, float* __restrict__ ymax, float* __restrict__ ymin)
{
  __shared__ double sh[32];
  statsmm_body<O>(A, Bq, idx, Nq, Nk, part, ymax, ymin,
                  blockIdx.x, blockIdx.y, gridDim.y, sh);
}

// ---------------- final pass: LINEAR (no gather). l is fp-monotone in y, so
// max_k l(y_k) = l(ymax) for gamma>=0 and l(ymin) for gamma<0 (bit-exact). -----
template<int O>
__global__ __launch_bounds__(256) void final_kernel(
    const float* __restrict__ ymax, const float* __restrict__ ymin,
    const double* __restrict__ part, int nsplit, double cnt,
    const float* __restrict__ gamma, const float* __restrict__ beta,
    float* __restrict__ fout, int Nq)
{
  constexpr int LO = ilog2c(O);
  constexpr int LO4 = ilog2c(O/4);
  __shared__ float smu[4], srs[4];
  int b = blockIdx.y;
  if (threadIdx.x < 4){
    int g = threadIdx.x;
    int t0 = b*4+g;
    double s1=0.0, s2=0.0;
    for (int i=0;i<nsplit;i++){ s1 += part[(t0*nsplit+i)*2]; s2 += part[(t0*nsplit+i)*2+1]; }
    double mean = s1/cnt;
    double var = s2/cnt - mean*mean;
    double rstd = 1.0 / sqrt(var + 1e-5);
    smu[g] = (float)mean;
    srs[g] = (float)rstd;
  }
  __syncthreads();
  int t = blockIdx.x*256 + threadIdx.x;
  if (t >= Nq*O) return;
  int o = t & (O-1);
  int q = t >> LO;
  int g = o >> LO4;
  float gam = gamma[o], bet = beta[o];
  size_t yo = (size_t)(b*Nq+q)*O + o;
  float ysel = (gam >= 0.f) ? ymax[yo] : ymin[yo];
  float yn = __fmul_rn(__fsub_rn(ysel, smu[g]), srs[g]);
  float yv = __fadd_rn(__fmul_rn(yn, gam), bet);
  fout[yo] = yv >= 0.f ? yv : 0.2f*yv;
}

// ---------------- gathers ----------------
static __device__ __forceinline__ void gatherc_body(const int* __restrict__ fidx,
    const float* __restrict__ pts, float* __restrict__ cq, int Nin, int Nout, int blk)
{
  int gid = blk*256 + threadIdx.x;
  if (gid >= BB*Nout) return;
  int b = gid / Nout;
  int i = gid - b*Nout;
  int src = fidx[b*Nout + i];
  #pragma unroll
  for (int c=0;c<3;c++) cq[gid*3+c] = pts[(b*Nin+src)*3+c];
}

__global__ __launch_bounds__(256) void gatherc_kernel(const int* __restrict__ fidx,
    const float* __restrict__ pts, float* __restrict__ cq, int Nin, int Nout)
{
  gatherc_body(fidx, pts, cq, Nin, Nout, blockIdx.x);
}

// ---------------- fused1: fps0 (32) | knn1-512chunk (1024) | proj (256) ------------
__global__ __launch_bounds__(256) void fused1_kernel(const float* __restrict__ x,
    const float* __restrict__ w_in, const float* __restrict__ b_in,
    float* __restrict__ f0, float* __restrict__ pd1, unsigned short* __restrict__ pi1,
    int* __restrict__ fidx0)
{
  __shared__ __align__(16) char sm[4096];
  int bid = blockIdx.x;
  if (bid < 32){
    __builtin_amdgcn_s_setprio(3);
    fps8_body(x, 512, fidx0, bid, sm);
  } else if (bid < 32+1024){
    int r = bid - 32;
    int b = r & 31; int rest = r >> 5;
    knn_part512_body(x, x, 2048, 2048, 4, pd1, pi1, b, rest & 7, rest >> 3, (float4*)sm);
  } else {
    proj_body(x, w_in, b_in, f0, bid - 1056);
  }
}

// ---------------- fused2: fps1(32) | knn2(512) | knn3(128) | merge1(256) | gemv1(2048)
__global__ __launch_bounds__(256) void fused2_kernel(const float* __restrict__ coorq1,
    const float* __restrict__ x,
    float* __restrict__ pd2, unsigned char* __restrict__ pi2,
    float* __restrict__ pd3, unsigned char* __restrict__ pi3,
    int* __restrict__ fidx1,
    const float* __restrict__ pd1, const unsigned short* __restrict__ pi1,
    int* __restrict__ idx1,
    const float* __restrict__ f0, const float* __restrict__ w1,
    float* __restrict__ A1, float* __restrict__ B1)
{
  __shared__ __align__(16) char sm[4096];
  int bid = blockIdx.x;
  if (bid < 32){
    __builtin_amdgcn_s_setprio(3);
    fps2_body(coorq1, 128, fidx1, bid, sm);
  } else if (bid < 32+512){
    int r = bid - 32;
    int b = r & 31; int rest = r >> 5;
    knn_part_body(coorq1, x, 512, 2048, 8, pd2, pi2, b, rest & 1, rest >> 1,
                  (float4*)sm, nullptr, 0);
  } else if (bid < 32+512+128){
    int r = bid - 544;
    int b = r & 31; int rest = r >> 5;
    knn_part_body(coorq1, coorq1, 512, 512, 2, pd3, pi3, b, rest & 1, rest >> 1,
                  (float4*)sm, nullptr, 0);
  } else if (bid < 928){
    knn_merge512_body(pd1, pi1, 2048, 4, idx1, bid - 672);
  } else if (bid < 1952){
    gemv_body<8,32,false>(f0, w1, A1, 2048, bid - 928);
  } else {
    gemv_body<8,32,true>(f0, w1, B1, 2048, bid - 1952);
  }
}

// ---------------- fused3: statsmm1(256) | merge2(64) | merge3(64) | knn4-ind(64) | gatherc4(16)
__global__ __launch_bounds__(256) void fused3_kernel(
    const float* __restrict__ A1, const float* __restrict__ B1,
    const int* __restrict__ idx1, double* __restrict__ part,
    float* __restrict__ ymax, float* __restrict__ ymin,
    const float* __restrict__ pd2, const unsigned char* __restrict__ pi2, int* __restrict__ idx2,
    const float* __restrict__ pd3, const unsigned char* __restrict__ pi3, int* __restrict__ idx3,
    const float* __restrict__ coorq1, const int* __restrict__ fidx1,
    float* __restrict__ pd4, unsigned char* __restrict__ pi4,
    float* __restrict__ coor_out)
{
  __shared__ __align__(16) char sm[4096];
  int bid = blockIdx.x;
  if (bid < 256){
    statsmm_body<32>(A1, B1, idx1, 2048, 2048, part, ymax, ymin,
                     bid >> 3, bid & 7, 8, (double*)sm);
  } else if (bid < 320){
    knn_merge_body(pd2, pi2, 512, 8, idx2, bid - 256);
  } else if (bid < 384){
    knn_merge_body(pd3, pi3, 512, 2, idx3, bid - 320);
  } else if (bid < 448){
    int r = bid - 384;
    int b = r & 31; int kc = r >> 5;
    knn_part_body(coorq1, coorq1, 128, 512, 2, pd4, pi4, b, 0, kc,
                  (float4*)sm, fidx1, 512);
  } else {
    gatherc_body(fidx1, coorq1, coor_out, 512, 128, bid - 448);
  }
}

// ---------------- fused4: gemv2 A(2048) + B-ind(512) | merge4(16) --------------------
__global__ __launch_bounds__(256) void fused4_kernel(const float* __restrict__ f1,
    const float* __restrict__ w2, float* __restrict__ A, float* __restrict__ Bq,
    const int* __restrict__ fidx0,
    const float* __restrict__ pd4, const unsigned char* __restrict__ pi4,
    int* __restrict__ idx4)
{
  int bid = blockIdx.x;
  if (bid < 2048) gemv_body<32,64,false>(f1, w2, A, 2048, bid);
  else if (bid < 2560) gemv_bodyBind<32,64,9>(f1, w2, Bq, bid - 2048, fidx0, 2048);
  else knn_merge_body(pd4, pi4, 128, 2, idx4, bid - 2560);
}

extern "C" void kernel_launch(void* const* d_in, const int* in_sizes, int n_in,
                              void* d_out, int out_size, void* d_ws, size_t ws_size,
                              hipStream_t stream)
{
  (void)in_sizes; (void)n_in; (void)out_size; (void)ws_size;
  const float* x    = (const float*)d_in[0];
  const float* w_in = (const float*)d_in[1];
  const float* b_in = (const float*)d_in[2];
  const float* w1 = (const float*)d_in[3];
  const float* g1 = (const float*)d_in[4];
  const float* be1= (const float*)d_in[5];
  const float* w2 = (const float*)d_in[6];
  const float* g2 = (const float*)d_in[7];
  const float* be2= (const float*)d_in[8];
  const float* w3 = (const float*)d_in[9];
  const float* g3 = (const float*)d_in[10];
  const float* be3= (const float*)d_in[11];
  const float* w4 = (const float*)d_in[12];
  const float* g4 = (const float*)d_in[13];
  const float* be4= (const float*)d_in[14];

  float* out = (float*)d_out;
  float* coor_out = out;                    // (32,128,3)
  float* f_out = out + BB*128*3;            // (32,128,256)

  char* ws = (char*)d_ws;
  size_t off = 0;
  auto alloc = [&](size_t bytes)->void*{ void* p = ws + off; off += (bytes + 255) & ~(size_t)255; return p; };

  // ---- persistent buffers (~37 MB) ----
  float* f0     = (float*)alloc((size_t)BB*2048*8*4);
  int*   idx1   = (int*)  alloc((size_t)BB*2048*16*4);
  float* f1     = (float*)alloc((size_t)BB*2048*32*4);
  double* part  = (double*)alloc((size_t)BB*4*8*2*8);
  int*   fidx0  = (int*)  alloc((size_t)BB*512*4);
  float* coorq1 = (float*)alloc((size_t)BB*512*3*4);
  int*   idx2   = (int*)  alloc((size_t)BB*512*16*4);
  float* f2     = (float*)alloc((size_t)BB*512*64*4);
  int*   idx3   = (int*)  alloc((size_t)BB*512*16*4);
  float* f3     = (float*)alloc((size_t)BB*512*64*4);
  int*   fidx1  = (int*)  alloc((size_t)BB*128*4);
  int*   idx4   = (int*)  alloc((size_t)BB*128*16*4);
  float* pd2          = (float*)alloc((size_t)BB*512*8*KNB*4);
  unsigned char* pi2  = (unsigned char*)alloc((size_t)BB*512*8*KNB);
  float* pd3          = (float*)alloc((size_t)BB*512*2*KNB*4);
  unsigned char* pi3  = (unsigned char*)alloc((size_t)BB*512*2*KNB);
  float* pd4          = (float*)alloc((size_t)BB*128*2*KNB*4);
  unsigned char* pi4  = (unsigned char*)alloc((size_t)BB*128*2*KNB);

  // ---- union region U (40 MB), phase-disjoint in time:
  // Phase A (fused1/2):   pd1[0,16M) pi1[16,24M) A1[24,32M) B1[32,40M)
  // Phase B (fused3+):    ymax[0,8M) ymin[8,16M)   (pd1 dead after merge1)
  // Phase C (stages 2-4): A[16,32M) Bq[32,36M)     (pi1/A1/B1 dead after statsmm1)
  char* U = (char*)alloc((size_t)40<<20);
  float* pd1          = (float*)U;
  unsigned short* pi1 = (unsigned short*)(U + ((size_t)16<<20));
  float* A1 = (float*)(U + ((size_t)24<<20));
  float* B1 = (float*)(U + ((size_t)32<<20));
  float* ymax = (float*)U;
  float* ymin = (float*)(U + ((size_t)8<<20));
  float* A  = (float*)(U + ((size_t)16<<20));
  float* Bq = (float*)(U + ((size_t)32<<20));

  auto cdiv = [](int a, int b){ return (a+b-1)/b; };

  // 1. fps0 | knn1 | proj
  fused1_kernel<<<1312,256,0,stream>>>(x, w_in, b_in, f0, pd1, pi1, fidx0);
  // 2. query coords for stages 2/3
  gatherc_kernel<<<cdiv(BB*512,256),256,0,stream>>>(fidx0, x, coorq1, 2048, 512);
  // 3. fps1 | knn2 | knn3 | merge1 | gemv1
  fused2_kernel<<<2976,256,0,stream>>>(coorq1, x, pd2, pi2, pd3, pi3, fidx1,
                                       pd1, pi1, idx1, f0, w1, A1, B1);
  // 4. statsmm1 | merge2 | merge3 | knn4-indirect | gatherc4
  fused3_kernel<<<464,256,0,stream>>>(A1, B1, idx1, part, ymax, ymin,
                                      pd2, pi2, idx2, pd3, pi3, idx3,
                                      coorq1, fidx1, pd4, pi4, coor_out);
  // 5. final1 (linear) -> f1
  final_kernel<32><<<dim3(cdiv(2048*32,256),BB),256,0,stream>>>(ymax, ymin, part, 8,
      8.0*2048*16, g1, be1, f1, 2048);
  // 6. gemv2 (A + B-indirect) | merge4
  fused4_kernel<<<2576,256,0,stream>>>(f1, w2, A, Bq, fidx0, pd4, pi4, idx4);
  // 7-8. stage 2
  statsmm_kernel<64><<<dim3(BB,8),256,0,stream>>>(A, Bq, idx2, 512, 2048, part, ymax, ymin);
  final_kernel<64><<<dim3(cdiv(512*64,256),BB),256,0,stream>>>(ymax, ymin, part, 8,
      16.0*512*16, g2, be2, f2, 512);
  // 9-11. stage 3
  gemv_dual_kernel<64,64,0,false><<<1024,256,0,stream>>>(f2, f2, w3, A, Bq,
      512, 512, 512, nullptr, 0);
  statsmm_kernel<64><<<dim3(BB,8),256,0,stream>>>(A, Bq, idx3, 512, 512, part, ymax, ymin);
  final_kernel<64><<<dim3(cdiv(512*64,256),BB),256,0,stream>>>(ymax, ymin, part, 8,
      16.0*512*16, g3, be3, f3, 512);
  // 12-14. stage 4 (B-indirect via fidx1)
  gemv_dual_kernel<64,256,7,true><<<2560,256,0,stream>>>(f3, f3, w4, A, Bq,
      512, 128, 2048, fidx1, 512);
  statsmm_kernel<256><<<dim3(BB,8),256,0,stream>>>(A, Bq, idx4, 128, 512, part, ymax, ymin);
  final_kernel<256><<<dim3(cdiv(128*256,256),BB),256,0,stream>>>(ymax, ymin, part, 8,
      64.0*128*16, g4, be4, f_out, 128);
}